// Round 7
// baseline (7741.473 us; speedup 1.0000x reference)
//
#include <hip/hip_runtime.h>
#include <hip/hip_bf16.h>
#include <stdint.h>
#include <math.h>

#define NB 128
#define NN 200
#define ND 128
#define NH 8
#define DH 16
#define NL 3
#define NF 2048
#define NT (NB * NN)
#define NSTEP 399

// ---------------- Threefry-2x32 (JAX-compatible) ----------------
__host__ __device__ inline void tf2x32(unsigned k0, unsigned k1, unsigned x0, unsigned x1,
                                       unsigned* o0, unsigned* o1) {
  unsigned ks[3] = {k0, k1, k0 ^ k1 ^ 0x1BD11BDAu};
  x0 += ks[0]; x1 += ks[1];
  const unsigned R[2][4] = {{13u, 15u, 26u, 6u}, {17u, 29u, 16u, 24u}};
#pragma unroll
  for (int i = 0; i < 5; ++i) {
#pragma unroll
    for (int j = 0; j < 4; ++j) {
      unsigned r = R[i & 1][j];
      x0 += x1;
      x1 = (x1 << r) | (x1 >> (32u - r));
      x1 ^= x0;
    }
    x0 += ks[(i + 1) % 3];
    x1 += ks[(i + 2) % 3] + (unsigned)(i + 1);
  }
  *o0 = x0; *o1 = x1;
}

// chain is serial (lane 0); leaf s-hashes parallel across the wave
__global__ void k_rng(unsigned* __restrict__ rng) {
  __shared__ unsigned ksh[2 * NSTEP];
  const int l = threadIdx.x;
  if (l == 0) {
    unsigned k0 = 0u, k1 = 42u;
    for (int t = 0; t < NSTEP; ++t) {
      ksh[2 * t] = k0; ksh[2 * t + 1] = k1;
      unsigned a0, a1;
      tf2x32(k0, k1, 0u, 0u, &a0, &a1);
      k0 = a0; k1 = a1;
    }
  }
  __syncthreads();
  for (int t = l; t < NSTEP; t += 64) {
    unsigned s0, s1;
    tf2x32(ksh[2 * t], ksh[2 * t + 1], 0u, 1u, &s0, &s1);
    rng[2 * t] = s0; rng[2 * t + 1] = s1;
  }
}

__global__ __launch_bounds__(256) void k_gum(const unsigned* __restrict__ rng, float* __restrict__ gum) {
  int idx = blockIdx.x * 256 + threadIdx.x;
  if (idx >= NSTEP * NT) return;
  int t = idx / NT, j = idx - t * NT;
  unsigned o0, o1;
  tf2x32(rng[2 * t], rng[2 * t + 1], 0u, (unsigned)j, &o0, &o1);
  unsigned bits = o0 ^ o1;
  float u01 = __uint_as_float((bits >> 9) | 0x3f800000u) - 1.0f;
  float uu = fmaxf(1.17549435082228751e-38f, u01);
  gum[idx] = (float)(-log(-log((double)uu)));
}

// ---------------- transpose f32->f32 ----------------
__global__ void k_tr(const float* __restrict__ src, float* __restrict__ dst, int R, int C) {
  int i = blockIdx.x * 256 + threadIdx.x;
  if (i >= R * C) return;
  int c = i / R, r = i - c * R;
  dst[i] = src[(size_t)r * C + c];
}

// ---------------- transpose + lossless f32->f64 convert ----------------
__global__ void k_trd(const float* __restrict__ src, double* __restrict__ dst, int R, int C) {
  int i = blockIdx.x * 256 + threadIdx.x;
  if (i >= R * C) return;
  int c = i / R, r = i - c * R;
  dst[i] = (double)src[(size_t)r * C + c];
}

// ---------------- embed ----------------
__global__ void k_embed(const float* __restrict__ coords, const float* __restrict__ dem,
                        const float* __restrict__ cap, const float* __restrict__ eW,
                        const float* __restrict__ eb, float* __restrict__ h, float* __restrict__ dr) {
  int gid = blockIdx.x * blockDim.x + threadIdx.x;
  int t = gid >> 7, d = gid & 127;
  int b = t / NN;
  float drv = dem[t] / cap[b];
  double acc = (double)eW[d * 3] * (double)coords[2 * t]
             + (double)eW[d * 3 + 1] * (double)coords[2 * t + 1]
             + (double)eW[d * 3 + 2] * (double)drv;
  h[gid] = (float)acc + eb[d];
  if (d == 0) dr[t] = drv;
}

// ---------------- qkv: 8 tokens/block, f64 weights (L2-resident, 393 KB) ----------------
#define QT 8
__global__ __launch_bounds__(384) void k_qkv(const float* __restrict__ h, const double* __restrict__ WT,
                                             const float* __restrict__ bias, float* __restrict__ qkv) {
  const int t0 = blockIdx.x * QT, j = threadIdx.x;
  __shared__ double hsh[ND][QT];
  for (int idx = j; idx < ND * QT; idx += 384) {
    int t = idx & 7, k = idx >> 3;
    hsh[k][t] = (double)h[(size_t)(t0 + t) * ND + k];
  }
  __syncthreads();
  double acc[QT];
#pragma unroll
  for (int t = 0; t < QT; ++t) acc[t] = 0.0;
  for (int k = 0; k < ND; ++k) {
    double w = WT[(size_t)k * 384 + j];
#pragma unroll
    for (int t = 0; t < QT; ++t) acc[t] += w * hsh[k][t];
  }
  float bv = bias[j];
#pragma unroll
  for (int t = 0; t < QT; ++t)
    qkv[(size_t)(t0 + t) * 384 + j] = (float)acc[t] + bv;
}

// ---------------- attention: wave-per-qn, ONE barrier ----------------
__global__ __launch_bounds__(256) void k_attn(const float* __restrict__ qkv, float* __restrict__ att) {
  const int b = blockIdx.x / NH, hh = blockIdx.x % NH, tid = threadIdx.x;
  const int lane = tid & 63, w = tid >> 6;
  __shared__ float qsh[NN][DH + 1];
  __shared__ float ksh[NN][DH + 1];
  __shared__ float vsh[NN][DH + 1];
  __shared__ float ashw[4][NN + 8];
  for (int idx = tid; idx < NN * DH; idx += 256) {
    int n = idx / DH, d2 = idx % DH;
    size_t base = (size_t)(b * NN + n) * 384 + hh * DH + d2;
    qsh[n][d2] = qkv[base];
    ksh[n][d2] = qkv[base + ND];
    vsh[n][d2] = qkv[base + 2 * ND];
  }
  __syncthreads();
  const int dd = lane & 15, q4 = lane >> 4;
  for (int qn = w; qn < NN; qn += 4) {
    double qv[DH];
#pragma unroll
    for (int d = 0; d < DH; ++d) qv[d] = (double)qsh[qn][d];
    float sf[4];
#pragma unroll
    for (int s = 0; s < 4; ++s) {
      int n = lane + 64 * s;
      if (n < NN) {
        double a = 0.0;
#pragma unroll
        for (int d = 0; d < DH; ++d) a += qv[d] * (double)ksh[n][d];
        sf[s] = (float)a / 4.0f;
      } else sf[s] = -3.0e38f;
    }
    float m = fmaxf(fmaxf(sf[0], sf[1]), fmaxf(sf[2], sf[3]));
    for (int off = 1; off < 64; off <<= 1) m = fmaxf(m, __shfl_xor(m, off, 64));
    double e[4];
    double esum = 0.0;
#pragma unroll
    for (int s = 0; s < 4; ++s) {
      int n = lane + 64 * s;
      e[s] = (n < NN) ? exp((double)(sf[s] - m)) : 0.0;
      esum += e[s];
    }
    for (int off = 1; off < 64; off <<= 1) esum += __shfl_xor(esum, off, 64);
#pragma unroll
    for (int s = 0; s < 4; ++s) {
      int n = lane + 64 * s;
      if (n < NN) ashw[w][n] = (float)(e[s] / esum);
    }
    double o = 0.0;
    for (int i = 0; i < 50; ++i) {
      int n = q4 * 50 + i;
      o += (double)ashw[w][n] * (double)vsh[n][dd];
    }
    o += __shfl_xor(o, 16, 64);
    o += __shfl_xor(o, 32, 64);
    if (lane < DH)
      att[(size_t)(b * NN + qn) * ND + hh * DH + lane] = (float)o;
  }
}

// ---------------- o-proj + residual + LN1; writes h64T[blk8][k][t] (f64, exact f32) ------
#define OT 4
__global__ __launch_bounds__(128) void k_oln(const float* __restrict__ att, const double* __restrict__ WoT,
                                             const float* __restrict__ bo, const float* __restrict__ g,
                                             const float* __restrict__ bb, const float* __restrict__ h,
                                             double* __restrict__ h64T) {
  const int t0 = blockIdx.x * OT, d = threadIdx.x;
  __shared__ double ash[ND][OT];
  __shared__ float xsh[OT][ND];
  __shared__ float mred[OT], sred[OT];
  for (int idx = d; idx < ND * OT; idx += 128) {
    int t = idx & 3, k = idx >> 2;
    ash[k][t] = (double)att[(size_t)(t0 + t) * ND + k];
  }
  __syncthreads();
  double acc[OT];
#pragma unroll
  for (int t = 0; t < OT; ++t) acc[t] = 0.0;
  for (int k = 0; k < ND; ++k) {
    double w = WoT[(size_t)k * ND + d];
#pragma unroll
    for (int t = 0; t < OT; ++t) acc[t] += w * ash[k][t];
  }
  float bv = bo[d];
#pragma unroll
  for (int t = 0; t < OT; ++t) {
    float o = (float)acc[t] + bv;
    xsh[t][d] = h[(size_t)(t0 + t) * ND + d] + o;
  }
  __syncthreads();
  if (d < OT) {
    double sv = 0.0;
    for (int k = 0; k < ND; ++k) sv += (double)xsh[d][k];
    float m = (float)(sv / 128.0);
    double sq = 0.0;
    for (int k = 0; k < ND; ++k) { float tf = xsh[d][k] - m; sq += (double)tf * (double)tf; }
    mred[d] = m;
    sred[d] = sqrtf((float)(sq / 128.0) + 1e-5f);
  }
  __syncthreads();
  const size_t blk8 = (size_t)(t0 >> 3);
  const int toff = t0 & 7;
#pragma unroll
  for (int t = 0; t < OT; ++t) {
    float tf = xsh[t][d] - mred[t];
    float hv = tf / sred[t] * g[d] + bb[d];
    h64T[blk8 * 1024 + (size_t)d * 8 + toff + t] = (double)hv;  // exact f32 value
  }
}

// ---------------- FFN v8: pipe-balanced; chains identical to R6 (passed) ----------------
// phase1: unchanged chains (j/thread=4, ascending k, h from h64T global uniform, zero cvt);
//         act stores now float4 into [t][2056] padded layout -> conflict-free writes.
// phase2: remap to 8d x 2t per thread (tq=lane>>4, d0=(lane&15)*8), W2T64 f64 (same values,
//         zero wd-cvt), acts read as 2 scalar broadcasts (2-bank, free) -> only 2 cvt/16 FMA.
//         chain content+order per (t,d,jg) unchanged: c outer, jj=(jg<<7)|((i+jg)&127).
// reduction: same slots, jg2=0..7 ascending, through the 65.8KB alias.
#define FT 8
#define FP 2056   // padded act row: (t*FP+j)%32 spreads t across banks
__global__ __launch_bounds__(512, 4) void k_ffn(float* __restrict__ h, const double* __restrict__ h64T,
                                                const double* __restrict__ W1T, const float* __restrict__ b1,
                                                const double* __restrict__ W2T64, const float* __restrict__ b2,
                                                const float* __restrict__ g, const float* __restrict__ bb) {
  const int tid = threadIdx.x;
  const int t0 = blockIdx.x * FT;
  const double* hp = h64T + (size_t)blockIdx.x * 1024;   // [k][t] for this 8-token block
  __shared__ double red_raw[FT * FP / 2];  // 65.8 KB: f32 acts [t][FP] | f64 reduction (8192)
  __shared__ float xsh[FT][ND];            // 4 KB
  __shared__ float mred[FT], sred[FT];
  float* fsh32 = (float*)red_raw;          // [t][FP]
  // ---- phase 1: f = relu(h @ W1^T + b1); j/thread=4, ascending-k chains (== R6) ----
  {
    const int j0 = tid * 4;
    double acc[4][FT];
#pragma unroll
    for (int a = 0; a < 4; ++a)
#pragma unroll
      for (int t = 0; t < FT; ++t) acc[a][t] = 0.0;
    const double* wrow = W1T + j0;
    for (int k = 0; k < ND; ++k) {
      double2 wa = *(const double2*)(wrow + (size_t)k * NF);
      double2 wb = *(const double2*)(wrow + (size_t)k * NF + 2);
      double wd[4] = {wa.x, wa.y, wb.x, wb.y};
      const double* hr = hp + k * 8;       // lane-invariant address
#pragma unroll
      for (int p = 0; p < 4; ++p) {
        double2 hv = *(const double2*)(hr + 2 * p);
#pragma unroll
        for (int a = 0; a < 4; ++a) {
          acc[a][2 * p] += wd[a] * hv.x;
          acc[a][2 * p + 1] += wd[a] * hv.y;
        }
      }
    }
    float bv0 = b1[j0], bv1 = b1[j0 + 1], bv2 = b1[j0 + 2], bv3 = b1[j0 + 3];
#pragma unroll
    for (int t = 0; t < FT; ++t) {
      float4 fw;
      fw.x = fmaxf((float)acc[0][t] + bv0, 0.0f);   // f32 round at tensor boundary (exact)
      fw.y = fmaxf((float)acc[1][t] + bv1, 0.0f);
      fw.z = fmaxf((float)acc[2][t] + bv2, 0.0f);
      fw.w = fmaxf((float)acc[3][t] + bv3, 0.0f);
      *(float4*)&fsh32[(size_t)t * FP + j0] = fw;   // lane-consecutive: conflict-free
    }
  }
  __syncthreads();
  // ---- phase 2: acc2 += f @ W2^T; 8d x 2t per thread; rotated-j chains (== R6) ----
  const int jg = tid >> 6;                 // wave id = jg chunk (0..7)
  const int lane = tid & 63;
  const int tq = lane >> 4;                // token pair: tokens {2tq, 2tq+1}
  const int dL = lane & 15, d0 = dL * 8;   // 8 d's per thread
  double acc2[8][2];
#pragma unroll
  for (int a = 0; a < 8; ++a) { acc2[a][0] = 0.0; acc2[a][1] = 0.0; }
  for (int c = 0; c < 2; ++c) {
    for (int i = 0; i < 128; ++i) {
      int jj = (jg << 7) | ((i + jg) & 127);
      int j = (c << 10) | jj;
      const double* wp = W2T64 + (size_t)j * ND + d0;
      double2 w01 = *(const double2*)(wp);
      double2 w23 = *(const double2*)(wp + 2);
      double2 w45 = *(const double2*)(wp + 4);
      double2 w67 = *(const double2*)(wp + 6);
      double f0 = (double)fsh32[(size_t)(2 * tq) * FP + j];       // broadcast, 2-bank
      double f1 = (double)fsh32[(size_t)(2 * tq + 1) * FP + j];
      double wd[8] = {w01.x, w01.y, w23.x, w23.y, w45.x, w45.y, w67.x, w67.y};
#pragma unroll
      for (int a = 0; a < 8; ++a) {
        acc2[a][0] += wd[a] * f0;
        acc2[a][1] += wd[a] * f1;
      }
    }
  }
  __syncthreads();   // act reads done; safe to overwrite as f64 reduction scratch
  // ---- reduction: red[(jg*8 + t)][d]; per-(t,d) partial order jg2 = 0..7 ascending ----
  double* red = red_raw;
#pragma unroll
  for (int a = 0; a < 8; ++a)
#pragma unroll
    for (int tt = 0; tt < 2; ++tt)
      red[((jg * 8 + tq * 2 + tt) << 7) + d0 + a] = acc2[a][tt];
  __syncthreads();
  for (int idx = tid; idx < ND * FT; idx += 512) {
    int t = idx >> 7, d = idx & 127;
    double s = 0.0;
#pragma unroll
    for (int jg2 = 0; jg2 < 8; ++jg2) s += red[((jg2 * 8 + t) << 7) + d];
    float o = (float)s + b2[d];
    float hres = (float)hp[(size_t)d * 8 + t];   // exact f32 value
    xsh[t][d] = hres + o;
  }
  __syncthreads();
  if (tid < FT) {
    double sv = 0.0;
    for (int d = 0; d < ND; ++d) sv += (double)xsh[tid][d];
    float m = (float)(sv / 128.0);
    double sq = 0.0;
    for (int d = 0; d < ND; ++d) { float tf = xsh[tid][d] - m; sq += (double)tf * (double)tf; }
    mred[tid] = m;
    sred[tid] = sqrtf((float)(sq / 128.0) + 1e-5f);
  }
  __syncthreads();
  for (int idx = tid; idx < ND * FT; idx += 512) {
    int d = idx & 127, t = idx >> 7;
    float tf = xsh[t][d] - mred[t];
    h[(size_t)(t0 + t) * ND + d] = tf / sred[t] * g[d] + bb[d];
  }
}

// ---------------- decode precompute ----------------
__global__ __launch_bounds__(128) void k_gctx(const float* __restrict__ h, float* __restrict__ gctx) {
  int b = blockIdx.x, d = threadIdx.x;
  double acc = 0.0;
  for (int n = 0; n < NN; ++n) acc += (double)h[(size_t)(b * NN + n) * ND + d];
  gctx[b * ND + d] = (float)(acc / 200.0);
}

#define KT 8
__global__ __launch_bounds__(128) void k_kmat(const float* __restrict__ h, const double* __restrict__ WkT,
                                              float* __restrict__ kmat) {
  const int t0 = blockIdx.x * KT, d = threadIdx.x;
  __shared__ double hsh[ND][KT];
  for (int idx = d; idx < ND * KT; idx += 128) {
    int t = idx & 7, k = idx >> 3;
    hsh[k][t] = (double)h[(size_t)(t0 + t) * ND + k];
  }
  __syncthreads();
  double acc[KT];
#pragma unroll
  for (int t = 0; t < KT; ++t) acc[t] = 0.0;
  for (int k = 0; k < ND; ++k) {
    double w = WkT[(size_t)k * ND + d];
#pragma unroll
    for (int t = 0; t < KT; ++t) acc[t] += w * hsh[k][t];
  }
#pragma unroll
  for (int t = 0; t < KT; ++t)
    kmat[(size_t)(t0 + t) * ND + d] = (float)acc[t];
}

__global__ __launch_bounds__(128) void k_prep1(const float* __restrict__ Wctx, const float* __restrict__ bcap,
                                               const float* __restrict__ Wcap, const float* __restrict__ bctx,
                                               double* __restrict__ t1, double* __restrict__ wu) {
  int k = threadIdx.x;
  double a = 0.0, c = 0.0;
  for (int m = 0; m < ND; ++m) {
    double wc = (double)Wctx[(size_t)k * 384 + 256 + m];
    a += wc * (double)bcap[m];
    c += wc * (double)Wcap[m];
  }
  t1[k] = a + (double)bctx[k];
  wu[k] = c;
}

__global__ __launch_bounds__(128) void k_M(const float* __restrict__ Wq, const float* __restrict__ Wctx,
                                           double* __restrict__ M) {
  int d = blockIdx.x, j = threadIdx.x;
  double acc = 0.0;
  for (int k = 0; k < ND; ++k)
    acc += (double)Wq[(size_t)d * ND + k] * (double)Wctx[(size_t)k * 384 + j];
  M[(size_t)d * ND + j] = acc;
}

__global__ __launch_bounds__(128) void k_u(const float* __restrict__ Wq, const double* __restrict__ wu,
                                           double* __restrict__ u) {
  int d = threadIdx.x;
  double acc = 0.0;
  for (int k = 0; k < ND; ++k) acc += (double)Wq[(size_t)d * ND + k] * wu[k];
  u[d] = acc;
}

__global__ __launch_bounds__(128) void k_t2(const float* __restrict__ Wctx, const float* __restrict__ gctx,
                                            double* __restrict__ t2) {
  int b = blockIdx.x, k = threadIdx.x;
  double acc = 0.0;
  for (int m = 0; m < ND; ++m)
    acc += (double)Wctx[(size_t)k * 384 + 128 + m] * (double)gctx[b * ND + m];
  t2[(size_t)b * ND + k] = acc;
}

__global__ __launch_bounds__(128) void k_vb(const float* __restrict__ Wq, const double* __restrict__ t2,
                                            const double* __restrict__ t1, double* __restrict__ vb) {
  int b = blockIdx.x, d = threadIdx.x;
  double acc = 0.0;
  for (int k = 0; k < ND; ++k)
    acc += (double)Wq[(size_t)d * ND + k] * (t2[(size_t)b * ND + k] + t1[k]);
  vb[(size_t)b * ND + d] = acc;
}

__global__ __launch_bounds__(256) void k_c01(const float* __restrict__ kmat, const double* __restrict__ vb,
                                             const double* __restrict__ u, float* __restrict__ c0, float* __restrict__ c1) {
  int t = blockIdx.x * 256 + threadIdx.x;
  if (t >= NT) return;
  int b = t / NN;
  double a0 = 0.0, a1 = 0.0;
  for (int d = 0; d < ND; ++d) {
    double km = (double)kmat[(size_t)t * ND + d];
    a0 += km * vb[(size_t)b * ND + d];
    a1 += km * u[d];
  }
  c0[t] = (float)a0;
  c1[t] = (float)a1;
}

// KM -> transposed store KMT[b][j][n]
__global__ __launch_bounds__(128) void k_KM(const float* __restrict__ kmat, const double* __restrict__ M,
                                            float* __restrict__ KMT) {
  const int t0 = blockIdx.x * KT, j = threadIdx.x;
  const int b = t0 / NN, toff = t0 % NN;
  __shared__ double ksh[ND][KT];
  for (int idx = j; idx < ND * KT; idx += 128) {
    int t = idx & 7, k = idx >> 3;
    ksh[k][t] = (double)kmat[(size_t)(t0 + t) * ND + k];
  }
  __syncthreads();
  double acc[KT];
#pragma unroll
  for (int t = 0; t < KT; ++t) acc[t] = 0.0;
  for (int d = 0; d < ND; ++d) {
    double m = M[(size_t)d * ND + j];
#pragma unroll
    for (int t = 0; t < KT; ++t) acc[t] += ksh[d][t] * m;
  }
#pragma unroll
  for (int t = 0; t < KT; ++t)
    KMT[(size_t)b * ND * NN + (size_t)j * NN + toff + t] = (float)acc[t];
}

// P[b][c][n]: coalesced KMT reads; 8 acc chains; ascending-j order
#define PC 8
__global__ __launch_bounds__(256) void k_P(const float* __restrict__ KMT, const float* __restrict__ h,
                                           float* __restrict__ P) {
  const int blk = blockIdx.x;
  const int b = blk / 25, c0 = (blk % 25) * PC;
  const int tid = threadIdx.x;
  __shared__ double h8[ND][PC];
  for (int idx = tid; idx < ND * PC; idx += 256) {
    int t = idx & 7, j = idx >> 3;
    h8[j][t] = (double)h[(size_t)(b * NN + c0 + t) * ND + j];
  }
  __syncthreads();
  if (tid < NN) {
    double acc[PC];
#pragma unroll
    for (int t = 0; t < PC; ++t) acc[t] = 0.0;
    const float* kb = KMT + (size_t)b * ND * NN + tid;
    for (int j = 0; j < ND; ++j) {
      double km = (double)kb[(size_t)j * NN];
#pragma unroll
      for (int t = 0; t < PC; ++t) acc[t] += km * h8[j][t];
    }
#pragma unroll
    for (int t = 0; t < PC; ++t)
      P[(size_t)(b * NN + c0 + t) * NN + tid] = (float)acc[t];
  }
}

// ---------------- decode: one wave / row, P[b] in LDS, gum prefetched ----------------
__global__ __launch_bounds__(64) void k_decode(const float* __restrict__ P, const float* __restrict__ c0,
                                               const float* __restrict__ c1, const float* __restrict__ dr,
                                               const float* __restrict__ gum, float* __restrict__ out) {
  __shared__ float Psh[NN * NN];  // 156.25 KB
  const int b = blockIdx.x, l = threadIdx.x;
  {
    const float4* src = (const float4*)(P + (size_t)b * NN * NN);
    float4* dst = (float4*)Psh;
    for (int i = l; i < (NN * NN) / 4; i += 64) dst[i] = src[i];
  }
  float drs4[4], c04[4], c14[4];
  int vis4[4];
#pragma unroll
  for (int s = 0; s < 4; ++s) {
    int n = l + 64 * s;
    bool valid = n < NN;
    drs4[s] = valid ? dr[b * NN + n] : 1e9f;
    c04[s] = valid ? c0[b * NN + n] : 0.0f;
    c14[s] = valid ? c1[b * NN + n] : 0.0f;
    vis4[s] = valid ? 0 : 1;
  }
  int cur = 0, done = 0;
  float rem = 1.0f, lpsum = 0.0f;
  if (l == 0) out[(size_t)b * 400] = 0.0f;
  __syncthreads();
  const float SQD = 11.3137084989847603f;
  float gv4[4];
#pragma unroll
  for (int s = 0; s < 4; ++s) {
    int n = l + 64 * s;
    gv4[s] = (n < NN) ? gum[(size_t)0 * NT + b * NN + n] : 0.0f;
  }
  for (int t = 0; t < NSTEP; ++t) {
    float gn4[4];
    if (t + 1 < NSTEP) {
      const float* grow = gum + (size_t)(t + 1) * NT + b * NN;
#pragma unroll
      for (int s = 0; s < 4; ++s) {
        int n = l + 64 * s;
        gn4[s] = (n < NN) ? grow[n] : 0.0f;
      }
    }
    const float* Prow = Psh + cur * NN;
    float Pv4[4];
#pragma unroll
    for (int s = 0; s < 4; ++s) {
      int n = l + 64 * s;
      Pv4[s] = (n < NN) ? Prow[n] : 0.0f;
    }
    bool lf = false, lns = false;
#pragma unroll
    for (int s = 0; s < 4; ++s) {
      int n = l + 64 * s;
      if (n >= 1 && n < NN && !vis4[s]) {
        lns = true;
        if (drs4[s] <= rem) lf = true;
      }
    }
    const int has_feas = (__ballot(lf) != 0ULL);
    const int all_served = (__ballot(lns) == 0ULL);
    const bool at_depot = (cur == 0) && !done, not_depot = (cur != 0) && !done;
    const bool depot_mask = (at_depot && has_feas) || (not_depot && has_feas && !all_served);
    float msk[4], sc[4];
#pragma unroll
    for (int s = 0; s < 4; ++s) {
      int n = l + 64 * s;
      if (n < NN) {
        double sd = (double)Pv4[s] + (double)c04[s] + (double)rem * (double)c14[s];
        float logit = (float)sd / SQD;
        bool infn = vis4[s] || (drs4[s] > rem) || (n == 0 && depot_mask);
        msk[s] = infn ? -1e9f : logit;
        sc[s] = msk[s] + gv4[s];
      } else {
        msk[s] = -3.0e38f;
        sc[s] = -3.0e38f;
      }
    }
    float bs = sc[0]; int bn = l; float bmsk = msk[0]; float mx = msk[0];
#pragma unroll
    for (int s = 1; s < 4; ++s) {
      int n = l + 64 * s;
      if (sc[s] > bs) { bs = sc[s]; bn = n; bmsk = msk[s]; }
      mx = fmaxf(mx, msk[s]);
    }
    for (int off = 1; off < 64; off <<= 1) {
      float os = __shfl_xor(bs, off, 64);
      int on = __shfl_xor(bn, off, 64);
      float ob = __shfl_xor(bmsk, off, 64);
      float om = __shfl_xor(mx, off, 64);
      if (os > bs || (os == bs && on < bn)) { bs = os; bn = on; bmsk = ob; }
      mx = fmaxf(mx, om);
    }
    float e = 0.0f;
#pragma unroll
    for (int s = 0; s < 4; ++s) e += expf(msk[s] - mx);
    for (int off = 1; off < 64; off <<= 1) e += __shfl_xor(e, off, 64);
    int sel = bn;
    float slp = (bmsk - mx) - logf(e);
    bool force = (all_served && cur != 0 && !done) || (not_depot && !has_feas) || done;
    if (force) { sel = 0; slp = 0.0f; }
    if (l == 0) out[(size_t)b * 400 + 1 + t] = (float)sel;
    lpsum += slp;
    bool isd = (sel == 0);
    float cand = drs4[sel >> 6];
    float take = __shfl(cand, sel & 63, 64);
    float nr = isd ? 1.0f : (rem - take);
    rem = fminf(fmaxf(nr, 0.0f), 1.0f);
    if (!isd && (sel & 63) == l) vis4[sel >> 6] = 1;
    if (all_served && sel == 0) done = 1;
    cur = sel;
#pragma unroll
    for (int s = 0; s < 4; ++s) gv4[s] = gn4[s];
  }
  if (l == 0) out[(size_t)NB * 400 + b] = lpsum;
}

// ---------------- host ----------------
extern "C" void kernel_launch(void* const* d_in, const int* in_sizes, int n_in,
                              void* d_out, int out_size, void* d_ws, size_t ws_size,
                              hipStream_t stream) {
  (void)in_sizes; (void)n_in; (void)out_size; (void)ws_size;
  const float* coords = (const float*)d_in[0];
  const float* dem    = (const float*)d_in[1];
  const float* cap    = (const float*)d_in[2];
  const float* eW     = (const float*)d_in[3];
  const float* eb     = (const float*)d_in[4];
  const float* Wqkv   = (const float*)d_in[5];
  const float* bqkv   = (const float*)d_in[6];
  const float* Wo     = (const float*)d_in[7];
  const float* bo     = (const float*)d_in[8];
  const float* W1     = (const float*)d_in[9];
  const float* b1     = (const float*)d_in[10];
  const float* W2     = (const float*)d_in[11];
  const float* b2     = (const float*)d_in[12];
  const float* ln1g   = (const float*)d_in[13];
  const float* ln1b   = (const float*)d_in[14];
  const float* ln2g   = (const float*)d_in[15];
  const float* ln2b   = (const float*)d_in[16];
  const float* Wq     = (const float*)d_in[17];
  const float* Wk     = (const float*)d_in[18];
  const float* Wcap   = (const float*)d_in[19];
  const float* bcap   = (const float*)d_in[20];
  const float* Wctx   = (const float*)d_in[21];
  const float* bctx   = (const float*)d_in[22];

  char* ws = (char*)d_ws;
  size_t off = 0;
  auto take = [&](size_t bytes) -> void* {
    void* p = ws + off;
    off += (bytes + 255) & ~(size_t)255;
    return p;
  };
  float* dr   = (float*)take((size_t)NT * 4);
  float* c0   = (float*)take((size_t)NT * 4);
  float* c1   = (float*)take((size_t)NT * 4);
  float* P    = (float*)take((size_t)NB * NN * NN * 4);
  unsigned* rng = (unsigned*)take((size_t)NSTEP * 2 * 4);
  float* h    = (float*)take((size_t)NT * ND * 4);
  float* qkv  = (float*)take((size_t)NT * 384 * 4);
  float* att  = (float*)take((size_t)NT * ND * 4);
  float* kmat = (float*)take((size_t)NT * ND * 4);
  float* gctx = (float*)take((size_t)NB * ND * 4);
  double* M   = (double*)take((size_t)ND * ND * 8);
  double* u   = (double*)take((size_t)ND * 8);
  double* t1  = (double*)take((size_t)ND * 8);
  double* wu  = (double*)take((size_t)ND * 8);
  double* t2  = (double*)take((size_t)NB * ND * 8);
  double* vb  = (double*)take((size_t)NB * ND * 8);
  double* W1T   = (double*)take((size_t)NL * NF * ND * 8);   // f64: phase-1 cvt-free
  double* W2T64 = (double*)take((size_t)NL * NF * ND * 8);   // f64: phase-2 cvt-free
  double* WqkvT = (double*)take((size_t)NL * 384 * ND * 8);
  double* WoT   = (double*)take((size_t)NL * ND * ND * 8);
  double* WkT   = (double*)take((size_t)ND * ND * 8);
  double* h64T  = (double*)take((size_t)NT * ND * 8);        // [blk8][k][t] post-LN1 acts
  float* KMT = qkv;   // alias: qkv (39.3 MB) dead after attention+oln; KMT = 13.1 MB
  float* gum = h;     // alias: h+qkv region (52 MB) >= gum (41 MB); written after k_P

  k_rng<<<1, 64, 0, stream>>>(rng);
  for (int i = 0; i < NL; ++i) {
    k_trd<<<(NF * ND + 255) / 256, 256, 0, stream>>>(W1 + (size_t)i * NF * ND, W1T + (size_t)i * NF * ND, NF, ND);
    k_trd<<<(NF * ND + 255) / 256, 256, 0, stream>>>(W2 + (size_t)i * ND * NF, W2T64 + (size_t)i * ND * NF, ND, NF);
    k_trd<<<(384 * ND + 255) / 256, 256, 0, stream>>>(Wqkv + (size_t)i * 384 * ND, WqkvT + (size_t)i * 384 * ND, 384, ND);
    k_trd<<<(ND * ND + 255) / 256, 256, 0, stream>>>(Wo + (size_t)i * ND * ND, WoT + (size_t)i * ND * ND, ND, ND);
  }
  k_trd<<<(ND * ND + 255) / 256, 256, 0, stream>>>(Wk, WkT, ND, ND);
  k_embed<<<(NT * ND) / 256, 256, 0, stream>>>(coords, dem, cap, eW, eb, h, dr);
  for (int i = 0; i < NL; ++i) {
    k_qkv<<<NT / QT, 384, 0, stream>>>(h, WqkvT + (size_t)i * 384 * ND, bqkv + (size_t)i * 384, qkv);
    k_attn<<<NB * NH, 256, 0, stream>>>(qkv, att);
    k_oln<<<NT / OT, 128, 0, stream>>>(att, WoT + (size_t)i * ND * ND, bo + (size_t)i * ND,
                                       ln1g + (size_t)i * ND, ln1b + (size_t)i * ND, h, h64T);
    k_ffn<<<NT / FT, 512, 0, stream>>>(h, h64T, W1T + (size_t)i * NF * ND, b1 + (size_t)i * NF,
                                       W2T64 + (size_t)i * ND * NF, b2 + (size_t)i * ND,
                                       ln2g + (size_t)i * ND, ln2b + (size_t)i * ND);
  }
  k_gctx<<<NB, 128, 0, stream>>>(h, gctx);
  k_kmat<<<NT / KT, 128, 0, stream>>>(h, WkT, kmat);
  k_prep1<<<1, 128, 0, stream>>>(Wctx, bcap, Wcap, bctx, t1, wu);
  k_M<<<ND, 128, 0, stream>>>(Wq, Wctx, M);
  k_u<<<1, 128, 0, stream>>>(Wq, wu, u);
  k_t2<<<NB, 128, 0, stream>>>(Wctx, gctx, t2);
  k_vb<<<NB, 128, 0, stream>>>(Wq, t2, t1, vb);
  k_c01<<<NT / 256, 256, 0, stream>>>(kmat, vb, u, c0, c1);
  k_KM<<<NT / KT, 128, 0, stream>>>(kmat, M, KMT);
  k_P<<<NB * 25, 256, 0, stream>>>(KMT, h, P);
  k_gum<<<(NSTEP * NT + 255) / 256, 256, 0, stream>>>(rng, gum);
  k_decode<<<NB, 64, 0, stream>>>(P, c0, c1, dr, gum, (float*)d_out);
}

// Round 8
// 4901.573 us; speedup vs baseline: 1.5794x; 1.5794x over previous
//
#include <hip/hip_runtime.h>
#include <hip/hip_bf16.h>
#include <stdint.h>
#include <math.h>

#define NB 128
#define NN 200
#define ND 128
#define NH 8
#define DH 16
#define NL 3
#define NF 2048
#define NT (NB * NN)
#define NSTEP 399

// ---------------- Threefry-2x32 (JAX-compatible) ----------------
__host__ __device__ inline void tf2x32(unsigned k0, unsigned k1, unsigned x0, unsigned x1,
                                       unsigned* o0, unsigned* o1) {
  unsigned ks[3] = {k0, k1, k0 ^ k1 ^ 0x1BD11BDAu};
  x0 += ks[0]; x1 += ks[1];
  const unsigned R[2][4] = {{13u, 15u, 26u, 6u}, {17u, 29u, 16u, 24u}};
#pragma unroll
  for (int i = 0; i < 5; ++i) {
#pragma unroll
    for (int j = 0; j < 4; ++j) {
      unsigned r = R[i & 1][j];
      x0 += x1;
      x1 = (x1 << r) | (x1 >> (32u - r));
      x1 ^= x0;
    }
    x0 += ks[(i + 1) % 3];
    x1 += ks[(i + 2) % 3] + (unsigned)(i + 1);
  }
  *o0 = x0; *o1 = x1;
}

// chain is serial (lane 0); leaf s-hashes parallel across the wave
__global__ void k_rng(unsigned* __restrict__ rng) {
  __shared__ unsigned ksh[2 * NSTEP];
  const int l = threadIdx.x;
  if (l == 0) {
    unsigned k0 = 0u, k1 = 42u;
    for (int t = 0; t < NSTEP; ++t) {
      ksh[2 * t] = k0; ksh[2 * t + 1] = k1;
      unsigned a0, a1;
      tf2x32(k0, k1, 0u, 0u, &a0, &a1);
      k0 = a0; k1 = a1;
    }
  }
  __syncthreads();
  for (int t = l; t < NSTEP; t += 64) {
    unsigned s0, s1;
    tf2x32(ksh[2 * t], ksh[2 * t + 1], 0u, 1u, &s0, &s1);
    rng[2 * t] = s0; rng[2 * t + 1] = s1;
  }
}

__global__ __launch_bounds__(256) void k_gum(const unsigned* __restrict__ rng, float* __restrict__ gum) {
  int idx = blockIdx.x * 256 + threadIdx.x;
  if (idx >= NSTEP * NT) return;
  int t = idx / NT, j = idx - t * NT;
  unsigned o0, o1;
  tf2x32(rng[2 * t], rng[2 * t + 1], 0u, (unsigned)j, &o0, &o1);
  unsigned bits = o0 ^ o1;
  float u01 = __uint_as_float((bits >> 9) | 0x3f800000u) - 1.0f;
  float uu = fmaxf(1.17549435082228751e-38f, u01);
  gum[idx] = (float)(-log(-log((double)uu)));
}

// ---------------- transpose f32->f32 ----------------
__global__ void k_tr(const float* __restrict__ src, float* __restrict__ dst, int R, int C) {
  int i = blockIdx.x * 256 + threadIdx.x;
  if (i >= R * C) return;
  int c = i / R, r = i - c * R;
  dst[i] = src[(size_t)r * C + c];
}

// ---------------- transpose + lossless f32->f64 convert ----------------
__global__ void k_trd(const float* __restrict__ src, double* __restrict__ dst, int R, int C) {
  int i = blockIdx.x * 256 + threadIdx.x;
  if (i >= R * C) return;
  int c = i / R, r = i - c * R;
  dst[i] = (double)src[(size_t)r * C + c];
}

// ---------------- embed (also seeds h64T[blk8][d][t]) ----------------
__global__ void k_embed(const float* __restrict__ coords, const float* __restrict__ dem,
                        const float* __restrict__ cap, const float* __restrict__ eW,
                        const float* __restrict__ eb, float* __restrict__ h, float* __restrict__ dr,
                        double* __restrict__ h64T) {
  int gid = blockIdx.x * blockDim.x + threadIdx.x;
  int t = gid >> 7, d = gid & 127;
  int b = t / NN;
  float drv = dem[t] / cap[b];
  double acc = (double)eW[d * 3] * (double)coords[2 * t]
             + (double)eW[d * 3 + 1] * (double)coords[2 * t + 1]
             + (double)eW[d * 3 + 2] * (double)drv;
  float hv = (float)acc + eb[d];
  h[gid] = hv;
  h64T[(size_t)(t >> 3) * 1024 + (size_t)d * 8 + (t & 7)] = (double)hv;  // exact f32
  if (d == 0) dr[t] = drv;
}

// ---------------- qkv: h from h64T (uniform global, zero LDS, zero cvt) ----------------
#define QT 8
__global__ __launch_bounds__(384) void k_qkv(const double* __restrict__ h64T, const double* __restrict__ WT,
                                             const float* __restrict__ bias, float* __restrict__ qkv) {
  const int t0 = blockIdx.x * QT, j = threadIdx.x;
  const double* hp = h64T + (size_t)blockIdx.x * 1024;   // [k][t]
  double acc[QT];
#pragma unroll
  for (int t = 0; t < QT; ++t) acc[t] = 0.0;
  for (int k = 0; k < ND; ++k) {
    double w = WT[(size_t)k * 384 + j];
    const double* hr = hp + k * 8;     // lane-invariant
    double2 h01 = *(const double2*)(hr);
    double2 h23 = *(const double2*)(hr + 2);
    double2 h45 = *(const double2*)(hr + 4);
    double2 h67 = *(const double2*)(hr + 6);
    acc[0] += w * h01.x; acc[1] += w * h01.y;
    acc[2] += w * h23.x; acc[3] += w * h23.y;
    acc[4] += w * h45.x; acc[5] += w * h45.y;
    acc[6] += w * h67.x; acc[7] += w * h67.y;
  }
  float bv = bias[j];
#pragma unroll
  for (int t = 0; t < QT; ++t)
    qkv[(size_t)(t0 + t) * 384 + j] = (float)acc[t] + bv;
}

// ---------------- attention: K hoisted to regs (one-time), att64T out ----------------
// QK chain identical: qv[d]*(double)kreg[s][d], d ascending; kreg values == ksh values.
// Output: round to f32 FIRST, then widen (bit-identical to old att f32 + oln's (double)).
__global__ __launch_bounds__(256) void k_attn(const float* __restrict__ qkv, double* __restrict__ att64T) {
  const int b = blockIdx.x / NH, hh = blockIdx.x % NH, tid = threadIdx.x;
  const int lane = tid & 63, w = tid >> 6;
  __shared__ float qsh[NN][DH + 1];
  __shared__ float ksh[NN][DH + 1];
  __shared__ float vsh[NN][DH + 1];
  __shared__ float ashw[4][NN + 8];
  for (int idx = tid; idx < NN * DH; idx += 256) {
    int n = idx / DH, d2 = idx % DH;
    size_t base = (size_t)(b * NN + n) * 384 + hh * DH + d2;
    qsh[n][d2] = qkv[base];
    ksh[n][d2] = qkv[base + ND];
    vsh[n][d2] = qkv[base + 2 * ND];
  }
  __syncthreads();
  float kreg[4][DH];   // one-time hoist: removes 64 LDS broadcasts per qn
#pragma unroll
  for (int s = 0; s < 4; ++s) {
    int n = lane + 64 * s;
    if (n < NN) {
#pragma unroll
      for (int d = 0; d < DH; ++d) kreg[s][d] = ksh[n][d];
    } else {
#pragma unroll
      for (int d = 0; d < DH; ++d) kreg[s][d] = 0.0f;
    }
  }
  const int dd = lane & 15, q4 = lane >> 4;
  for (int qn = w; qn < NN; qn += 4) {
    double qv[DH];
#pragma unroll
    for (int d = 0; d < DH; ++d) qv[d] = (double)qsh[qn][d];
    float sf[4];
#pragma unroll
    for (int s = 0; s < 4; ++s) {
      int n = lane + 64 * s;
      if (n < NN) {
        double a = 0.0;
#pragma unroll
        for (int d = 0; d < DH; ++d) a += qv[d] * (double)kreg[s][d];
        sf[s] = (float)a / 4.0f;
      } else sf[s] = -3.0e38f;
    }
    float m = fmaxf(fmaxf(sf[0], sf[1]), fmaxf(sf[2], sf[3]));
    for (int off = 1; off < 64; off <<= 1) m = fmaxf(m, __shfl_xor(m, off, 64));
    double e[4];
    double esum = 0.0;
#pragma unroll
    for (int s = 0; s < 4; ++s) {
      int n = lane + 64 * s;
      e[s] = (n < NN) ? exp((double)(sf[s] - m)) : 0.0;
      esum += e[s];
    }
    for (int off = 1; off < 64; off <<= 1) esum += __shfl_xor(esum, off, 64);
#pragma unroll
    for (int s = 0; s < 4; ++s) {
      int n = lane + 64 * s;
      if (n < NN) ashw[w][n] = (float)(e[s] / esum);
    }
    double o = 0.0;
    for (int i = 0; i < 50; ++i) {
      int n = q4 * 50 + i;
      o += (double)ashw[w][n] * (double)vsh[n][dd];
    }
    o += __shfl_xor(o, 16, 64);
    o += __shfl_xor(o, 32, 64);
    if (lane < DH) {
      int tq = b * NN + qn;
      float of = (float)o;                       // f32 round (== old att store)
      att64T[(size_t)(tq >> 2) * 512 + (size_t)(hh * DH + lane) * 4 + (tq & 3)] = (double)of;
    }
  }
}

// ---------------- o-proj + residual + LN1: att from att64T (uniform global) ------------
#define OT 4
__global__ __launch_bounds__(128) void k_oln(const double* __restrict__ att64T, const double* __restrict__ WoT,
                                             const float* __restrict__ bo, const float* __restrict__ g,
                                             const float* __restrict__ bb, const float* __restrict__ h,
                                             double* __restrict__ h64T) {
  const int t0 = blockIdx.x * OT, d = threadIdx.x;
  __shared__ float xsh[OT][ND];
  __shared__ float mred[OT], sred[OT];
  const double* ap = att64T + (size_t)blockIdx.x * 512;   // [k][t] 128x4
  double acc[OT];
#pragma unroll
  for (int t = 0; t < OT; ++t) acc[t] = 0.0;
  for (int k = 0; k < ND; ++k) {
    double w = WoT[(size_t)k * ND + d];
    const double* ar = ap + k * 4;    // lane-invariant
    double2 a01 = *(const double2*)(ar);
    double2 a23 = *(const double2*)(ar + 2);
    acc[0] += w * a01.x; acc[1] += w * a01.y;
    acc[2] += w * a23.x; acc[3] += w * a23.y;
  }
  float bv = bo[d];
#pragma unroll
  for (int t = 0; t < OT; ++t) {
    float o = (float)acc[t] + bv;
    xsh[t][d] = h[(size_t)(t0 + t) * ND + d] + o;
  }
  __syncthreads();
  if (d < OT) {
    double sv = 0.0;
    for (int k = 0; k < ND; ++k) sv += (double)xsh[d][k];
    float m = (float)(sv / 128.0);
    double sq = 0.0;
    for (int k = 0; k < ND; ++k) { float tf = xsh[d][k] - m; sq += (double)tf * (double)tf; }
    mred[d] = m;
    sred[d] = sqrtf((float)(sq / 128.0) + 1e-5f);
  }
  __syncthreads();
  const size_t blk8 = (size_t)(t0 >> 3);
  const int toff = t0 & 7;
#pragma unroll
  for (int t = 0; t < OT; ++t) {
    float tf = xsh[t][d] - mred[t];
    float hv = tf / sred[t] * g[d] + bb[d];
    h64T[blk8 * 1024 + (size_t)d * 8 + toff + t] = (double)hv;  // exact f32 value
  }
}

// ---------------- FFN v9: R6 chains + verified [t][FP] act layout + W2T f32 -------------
// phase1: j/thread=4, ascending-k chains, h from h64T global uniform (zero LDS, zero cvt);
//         float4 act stores into padded [t][FP] (R7-verified correct).
// phase2: R6 map (jg=wave, th=lane>>5 token-half, 4 d's); W2T f32 (R6 values); acts read
//         as 4 scalar broadcasts (2-address multicast, free); c outer, rotated jj.
// reduction: same slots, jg2=0..7 ascending. Epilogue also writes h64T for next layer.
#define FT 8
#define FP 2056
__global__ __launch_bounds__(512, 4) void k_ffn(float* __restrict__ h, double* __restrict__ h64T,
                                                const double* __restrict__ W1T, const float* __restrict__ b1,
                                                const float* __restrict__ W2T, const float* __restrict__ b2,
                                                const float* __restrict__ g, const float* __restrict__ bb) {
  const int tid = threadIdx.x;
  const int t0 = blockIdx.x * FT;
  const double* hp = h64T + (size_t)blockIdx.x * 1024;   // [k][t] for this 8-token block
  __shared__ double red_raw[FT * FP / 2];  // 65.8 KB: f32 acts [t][FP] | f64 reduction (8192)
  __shared__ float xsh[FT][ND];            // 4 KB
  __shared__ float mred[FT], sred[FT];
  float* fsh32 = (float*)red_raw;          // [t][FP]
  // ---- phase 1: f = relu(h @ W1^T + b1); j/thread=4, ascending-k chains (== R6) ----
  {
    const int j0 = tid * 4;
    double acc[4][FT];
#pragma unroll
    for (int a = 0; a < 4; ++a)
#pragma unroll
      for (int t = 0; t < FT; ++t) acc[a][t] = 0.0;
    const double* wrow = W1T + j0;
    for (int k = 0; k < ND; ++k) {
      double2 wa = *(const double2*)(wrow + (size_t)k * NF);
      double2 wb = *(const double2*)(wrow + (size_t)k * NF + 2);
      double wd[4] = {wa.x, wa.y, wb.x, wb.y};
      const double* hr = hp + k * 8;       // lane-invariant address
#pragma unroll
      for (int p = 0; p < 4; ++p) {
        double2 hv = *(const double2*)(hr + 2 * p);
#pragma unroll
        for (int a = 0; a < 4; ++a) {
          acc[a][2 * p] += wd[a] * hv.x;
          acc[a][2 * p + 1] += wd[a] * hv.y;
        }
      }
    }
    float bv0 = b1[j0], bv1 = b1[j0 + 1], bv2 = b1[j0 + 2], bv3 = b1[j0 + 3];
#pragma unroll
    for (int t = 0; t < FT; ++t) {
      float4 fw;
      fw.x = fmaxf((float)acc[0][t] + bv0, 0.0f);   // f32 round at tensor boundary (exact)
      fw.y = fmaxf((float)acc[1][t] + bv1, 0.0f);
      fw.z = fmaxf((float)acc[2][t] + bv2, 0.0f);
      fw.w = fmaxf((float)acc[3][t] + bv3, 0.0f);
      *(float4*)&fsh32[(size_t)t * FP + j0] = fw;   // lane-consecutive store
    }
  }
  __syncthreads();
  // ---- phase 2: acc2 += f @ W2^T; R6 map + rotated-j chains; scalar act broadcasts ----
  const int jg = tid >> 6;                 // wave id = jg chunk (0..7)
  const int lane = tid & 63;
  const int th = lane >> 5;                // token-half (0: t=0..3, 1: t=4..7)
  const int dlo = lane & 31, d0 = dlo << 2;
  double acc2[4][4];
#pragma unroll
  for (int a = 0; a < 4; ++a)
#pragma unroll
    for (int t = 0; t < 4; ++t) acc2[a][t] = 0.0;
  for (int c = 0; c < 2; ++c) {
    for (int i = 0; i < 128; ++i) {
      int jj = (jg << 7) | ((i + jg) & 127);
      int j = (c << 10) | jj;
      float4 wv = *(const float4*)(W2T + (size_t)j * ND + d0);
      double fv[4];
#pragma unroll
      for (int tt = 0; tt < 4; ++tt)
        fv[tt] = (double)fsh32[(size_t)(th * 4 + tt) * FP + j];
      double wd[4] = {(double)wv.x, (double)wv.y, (double)wv.z, (double)wv.w};
#pragma unroll
      for (int a = 0; a < 4; ++a)
#pragma unroll
        for (int t = 0; t < 4; ++t) acc2[a][t] += wd[a] * fv[t];
    }
  }
  __syncthreads();   // act reads done; safe to overwrite as f64 reduction scratch
  // ---- reduction: red[(jg*8 + t)][d]; per-(t,d) partial order jg2 = 0..7 ascending ----
  double* red = red_raw;
#pragma unroll
  for (int a = 0; a < 4; ++a)
#pragma unroll
    for (int t = 0; t < 4; ++t)
      red[((jg * 8 + th * 4 + t) << 7) + d0 + a] = acc2[a][t];
  __syncthreads();
  for (int idx = tid; idx < ND * FT; idx += 512) {
    int t = idx >> 7, d = idx & 127;
    double s = 0.0;
#pragma unroll
    for (int jg2 = 0; jg2 < 8; ++jg2) s += red[((jg2 * 8 + t) << 7) + d];
    float o = (float)s + b2[d];
    float hres = (float)hp[(size_t)d * 8 + t];   // exact f32 value
    xsh[t][d] = hres + o;
  }
  __syncthreads();
  if (tid < FT) {
    double sv = 0.0;
    for (int d = 0; d < ND; ++d) sv += (double)xsh[tid][d];
    float m = (float)(sv / 128.0);
    double sq = 0.0;
    for (int d = 0; d < ND; ++d) { float tf = xsh[tid][d] - m; sq += (double)tf * (double)tf; }
    mred[tid] = m;
    sred[tid] = sqrtf((float)(sq / 128.0) + 1e-5f);
  }
  __syncthreads();
  for (int idx = tid; idx < ND * FT; idx += 512) {
    int d = idx & 127, t = idx >> 7;
    float tf = xsh[t][d] - mred[t];
    float hv = tf / sred[t] * g[d] + bb[d];
    h[(size_t)(t0 + t) * ND + d] = hv;
    h64T[(size_t)blockIdx.x * 1024 + (size_t)d * 8 + t] = (double)hv;  // for next qkv
  }
}

// ---------------- decode precompute ----------------
__global__ __launch_bounds__(128) void k_gctx(const float* __restrict__ h, float* __restrict__ gctx) {
  int b = blockIdx.x, d = threadIdx.x;
  double acc = 0.0;
  for (int n = 0; n < NN; ++n) acc += (double)h[(size_t)(b * NN + n) * ND + d];
  gctx[b * ND + d] = (float)(acc / 200.0);
}

#define KT 8
__global__ __launch_bounds__(128) void k_kmat(const double* __restrict__ h64T, const double* __restrict__ WkT,
                                              float* __restrict__ kmat) {
  const int t0 = blockIdx.x * KT, d = threadIdx.x;
  const double* hp = h64T + (size_t)blockIdx.x * 1024;   // [k][t]
  double acc[KT];
#pragma unroll
  for (int t = 0; t < KT; ++t) acc[t] = 0.0;
  for (int k = 0; k < ND; ++k) {
    double w = WkT[(size_t)k * ND + d];
    const double* hr = hp + k * 8;     // lane-invariant
    double2 h01 = *(const double2*)(hr);
    double2 h23 = *(const double2*)(hr + 2);
    double2 h45 = *(const double2*)(hr + 4);
    double2 h67 = *(const double2*)(hr + 6);
    acc[0] += w * h01.x; acc[1] += w * h01.y;
    acc[2] += w * h23.x; acc[3] += w * h23.y;
    acc[4] += w * h45.x; acc[5] += w * h45.y;
    acc[6] += w * h67.x; acc[7] += w * h67.y;
  }
#pragma unroll
  for (int t = 0; t < KT; ++t)
    kmat[(size_t)(t0 + t) * ND + d] = (float)acc[t];
}

__global__ __launch_bounds__(128) void k_prep1(const float* __restrict__ Wctx, const float* __restrict__ bcap,
                                               const float* __restrict__ Wcap, const float* __restrict__ bctx,
                                               double* __restrict__ t1, double* __restrict__ wu) {
  int k = threadIdx.x;
  double a = 0.0, c = 0.0;
  for (int m = 0; m < ND; ++m) {
    double wc = (double)Wctx[(size_t)k * 384 + 256 + m];
    a += wc * (double)bcap[m];
    c += wc * (double)Wcap[m];
  }
  t1[k] = a + (double)bctx[k];
  wu[k] = c;
}

__global__ __launch_bounds__(128) void k_M(const float* __restrict__ Wq, const float* __restrict__ Wctx,
                                           double* __restrict__ M) {
  int d = blockIdx.x, j = threadIdx.x;
  double acc = 0.0;
  for (int k = 0; k < ND; ++k)
    acc += (double)Wq[(size_t)d * ND + k] * (double)Wctx[(size_t)k * 384 + j];
  M[(size_t)d * ND + j] = acc;
}

__global__ __launch_bounds__(128) void k_u(const float* __restrict__ Wq, const double* __restrict__ wu,
                                           double* __restrict__ u) {
  int d = threadIdx.x;
  double acc = 0.0;
  for (int k = 0; k < ND; ++k) acc += (double)Wq[(size_t)d * ND + k] * wu[k];
  u[d] = acc;
}

__global__ __launch_bounds__(128) void k_t2(const float* __restrict__ Wctx, const float* __restrict__ gctx,
                                            double* __restrict__ t2) {
  int b = blockIdx.x, k = threadIdx.x;
  double acc = 0.0;
  for (int m = 0; m < ND; ++m)
    acc += (double)Wctx[(size_t)k * 384 + 128 + m] * (double)gctx[b * ND + m];
  t2[(size_t)b * ND + k] = acc;
}

__global__ __launch_bounds__(128) void k_vb(const float* __restrict__ Wq, const double* __restrict__ t2,
                                            const double* __restrict__ t1, double* __restrict__ vb) {
  int b = blockIdx.x, d = threadIdx.x;
  double acc = 0.0;
  for (int k = 0; k < ND; ++k)
    acc += (double)Wq[(size_t)d * ND + k] * (t2[(size_t)b * ND + k] + t1[k]);
  vb[(size_t)b * ND + d] = acc;
}

__global__ __launch_bounds__(256) void k_c01(const float* __restrict__ kmat, const double* __restrict__ vb,
                                             const double* __restrict__ u, float* __restrict__ c0, float* __restrict__ c1) {
  int t = blockIdx.x * 256 + threadIdx.x;
  if (t >= NT) return;
  int b = t / NN;
  double a0 = 0.0, a1 = 0.0;
  for (int d = 0; d < ND; ++d) {
    double km = (double)kmat[(size_t)t * ND + d];
    a0 += km * vb[(size_t)b * ND + d];
    a1 += km * u[d];
  }
  c0[t] = (float)a0;
  c1[t] = (float)a1;
}

// KM -> transposed store KMT[b][j][n]
__global__ __launch_bounds__(128) void k_KM(const float* __restrict__ kmat, const double* __restrict__ M,
                                            float* __restrict__ KMT) {
  const int t0 = blockIdx.x * KT, j = threadIdx.x;
  const int b = t0 / NN, toff = t0 % NN;
  __shared__ double ksh[ND][KT];
  for (int idx = j; idx < ND * KT; idx += 128) {
    int t = idx & 7, k = idx >> 3;
    ksh[k][t] = (double)kmat[(size_t)(t0 + t) * ND + k];
  }
  __syncthreads();
  double acc[KT];
#pragma unroll
  for (int t = 0; t < KT; ++t) acc[t] = 0.0;
  for (int d = 0; d < ND; ++d) {
    double m = M[(size_t)d * ND + j];
#pragma unroll
    for (int t = 0; t < KT; ++t) acc[t] += ksh[d][t] * m;
  }
#pragma unroll
  for (int t = 0; t < KT; ++t)
    KMT[(size_t)b * ND * NN + (size_t)j * NN + toff + t] = (float)acc[t];
}

// P[b][c][n]: coalesced KMT reads; 8 acc chains; ascending-j order
#define PC 8
__global__ __launch_bounds__(256) void k_P(const float* __restrict__ KMT, const float* __restrict__ h,
                                           float* __restrict__ P) {
  const int blk = blockIdx.x;
  const int b = blk / 25, c0 = (blk % 25) * PC;
  const int tid = threadIdx.x;
  __shared__ double h8[ND][PC];
  for (int idx = tid; idx < ND * PC; idx += 256) {
    int t = idx & 7, j = idx >> 3;
    h8[j][t] = (double)h[(size_t)(b * NN + c0 + t) * ND + j];
  }
  __syncthreads();
  if (tid < NN) {
    double acc[PC];
#pragma unroll
    for (int t = 0; t < PC; ++t) acc[t] = 0.0;
    const float* kb = KMT + (size_t)b * ND * NN + tid;
    for (int j = 0; j < ND; ++j) {
      double km = (double)kb[(size_t)j * NN];
#pragma unroll
      for (int t = 0; t < PC; ++t) acc[t] += km * h8[j][t];
    }
#pragma unroll
    for (int t = 0; t < PC; ++t)
      P[(size_t)(b * NN + c0 + t) * NN + tid] = (float)acc[t];
  }
}

// ---------------- decode: one wave / row, P[b] in LDS, gum prefetched ----------------
__global__ __launch_bounds__(64) void k_decode(const float* __restrict__ P, const float* __restrict__ c0,
                                               const float* __restrict__ c1, const float* __restrict__ dr,
                                               const float* __restrict__ gum, float* __restrict__ out) {
  __shared__ float Psh[NN * NN];  // 156.25 KB
  const int b = blockIdx.x, l = threadIdx.x;
  {
    const float4* src = (const float4*)(P + (size_t)b * NN * NN);
    float4* dst = (float4*)Psh;
    for (int i = l; i < (NN * NN) / 4; i += 64) dst[i] = src[i];
  }
  float drs4[4], c04[4], c14[4];
  int vis4[4];
#pragma unroll
  for (int s = 0; s < 4; ++s) {
    int n = l + 64 * s;
    bool valid = n < NN;
    drs4[s] = valid ? dr[b * NN + n] : 1e9f;
    c04[s] = valid ? c0[b * NN + n] : 0.0f;
    c14[s] = valid ? c1[b * NN + n] : 0.0f;
    vis4[s] = valid ? 0 : 1;
  }
  int cur = 0, done = 0;
  float rem = 1.0f, lpsum = 0.0f;
  if (l == 0) out[(size_t)b * 400] = 0.0f;
  __syncthreads();
  const float SQD = 11.3137084989847603f;
  float gv4[4];
#pragma unroll
  for (int s = 0; s < 4; ++s) {
    int n = l + 64 * s;
    gv4[s] = (n < NN) ? gum[(size_t)0 * NT + b * NN + n] : 0.0f;
  }
  for (int t = 0; t < NSTEP; ++t) {
    float gn4[4];
    if (t + 1 < NSTEP) {
      const float* grow = gum + (size_t)(t + 1) * NT + b * NN;
#pragma unroll
      for (int s = 0; s < 4; ++s) {
        int n = l + 64 * s;
        gn4[s] = (n < NN) ? grow[n] : 0.0f;
      }
    }
    const float* Prow = Psh + cur * NN;
    float Pv4[4];
#pragma unroll
    for (int s = 0; s < 4; ++s) {
      int n = l + 64 * s;
      Pv4[s] = (n < NN) ? Prow[n] : 0.0f;
    }
    bool lf = false, lns = false;
#pragma unroll
    for (int s = 0; s < 4; ++s) {
      int n = l + 64 * s;
      if (n >= 1 && n < NN && !vis4[s]) {
        lns = true;
        if (drs4[s] <= rem) lf = true;
      }
    }
    const int has_feas = (__ballot(lf) != 0ULL);
    const int all_served = (__ballot(lns) == 0ULL);
    const bool at_depot = (cur == 0) && !done, not_depot = (cur != 0) && !done;
    const bool depot_mask = (at_depot && has_feas) || (not_depot && has_feas && !all_served);
    float msk[4], sc[4];
#pragma unroll
    for (int s = 0; s < 4; ++s) {
      int n = l + 64 * s;
      if (n < NN) {
        double sd = (double)Pv4[s] + (double)c04[s] + (double)rem * (double)c14[s];
        float logit = (float)sd / SQD;
        bool infn = vis4[s] || (drs4[s] > rem) || (n == 0 && depot_mask);
        msk[s] = infn ? -1e9f : logit;
        sc[s] = msk[s] + gv4[s];
      } else {
        msk[s] = -3.0e38f;
        sc[s] = -3.0e38f;
      }
    }
    float bs = sc[0]; int bn = l; float bmsk = msk[0]; float mx = msk[0];
#pragma unroll
    for (int s = 1; s < 4; ++s) {
      int n = l + 64 * s;
      if (sc[s] > bs) { bs = sc[s]; bn = n; bmsk = msk[s]; }
      mx = fmaxf(mx, msk[s]);
    }
    for (int off = 1; off < 64; off <<= 1) {
      float os = __shfl_xor(bs, off, 64);
      int on = __shfl_xor(bn, off, 64);
      float ob = __shfl_xor(bmsk, off, 64);
      float om = __shfl_xor(mx, off, 64);
      if (os > bs || (os == bs && on < bn)) { bs = os; bn = on; bmsk = ob; }
      mx = fmaxf(mx, om);
    }
    float e = 0.0f;
#pragma unroll
    for (int s = 0; s < 4; ++s) e += expf(msk[s] - mx);
    for (int off = 1; off < 64; off <<= 1) e += __shfl_xor(e, off, 64);
    int sel = bn;
    float slp = (bmsk - mx) - logf(e);
    bool force = (all_served && cur != 0 && !done) || (not_depot && !has_feas) || done;
    if (force) { sel = 0; slp = 0.0f; }
    if (l == 0) out[(size_t)b * 400 + 1 + t] = (float)sel;
    lpsum += slp;
    bool isd = (sel == 0);
    float cand = drs4[sel >> 6];
    float take = __shfl(cand, sel & 63, 64);
    float nr = isd ? 1.0f : (rem - take);
    rem = fminf(fmaxf(nr, 0.0f), 1.0f);
    if (!isd && (sel & 63) == l) vis4[sel >> 6] = 1;
    if (all_served && sel == 0) done = 1;
    cur = sel;
#pragma unroll
    for (int s = 0; s < 4; ++s) gv4[s] = gn4[s];
  }
  if (l == 0) out[(size_t)NB * 400 + b] = lpsum;
}

// ---------------- host ----------------
extern "C" void kernel_launch(void* const* d_in, const int* in_sizes, int n_in,
                              void* d_out, int out_size, void* d_ws, size_t ws_size,
                              hipStream_t stream) {
  (void)in_sizes; (void)n_in; (void)out_size; (void)ws_size;
  const float* coords = (const float*)d_in[0];
  const float* dem    = (const float*)d_in[1];
  const float* cap    = (const float*)d_in[2];
  const float* eW     = (const float*)d_in[3];
  const float* eb     = (const float*)d_in[4];
  const float* Wqkv   = (const float*)d_in[5];
  const float* bqkv   = (const float*)d_in[6];
  const float* Wo     = (const float*)d_in[7];
  const float* bo     = (const float*)d_in[8];
  const float* W1     = (const float*)d_in[9];
  const float* b1     = (const float*)d_in[10];
  const float* W2     = (const float*)d_in[11];
  const float* b2     = (const float*)d_in[12];
  const float* ln1g   = (const float*)d_in[13];
  const float* ln1b   = (const float*)d_in[14];
  const float* ln2g   = (const float*)d_in[15];
  const float* ln2b   = (const float*)d_in[16];
  const float* Wq     = (const float*)d_in[17];
  const float* Wk     = (const float*)d_in[18];
  const float* Wcap   = (const float*)d_in[19];
  const float* bcap   = (const float*)d_in[20];
  const float* Wctx   = (const float*)d_in[21];
  const float* bctx   = (const float*)d_in[22];

  char* ws = (char*)d_ws;
  size_t off = 0;
  auto take = [&](size_t bytes) -> void* {
    void* p = ws + off;
    off += (bytes + 255) & ~(size_t)255;
    return p;
  };
  float* dr   = (float*)take((size_t)NT * 4);
  float* c0   = (float*)take((size_t)NT * 4);
  float* c1   = (float*)take((size_t)NT * 4);
  float* P    = (float*)take((size_t)NB * NN * NN * 4);
  unsigned* rng = (unsigned*)take((size_t)NSTEP * 2 * 4);
  float* h    = (float*)take((size_t)NT * ND * 4);
  float* qkv  = (float*)take((size_t)NT * 384 * 4);
  double* att64T = (double*)take((size_t)NT * ND * 8);       // [blk4][ch][t] attn out (f64 of exact f32)
  float* kmat = (float*)take((size_t)NT * ND * 4);
  float* gctx = (float*)take((size_t)NB * ND * 4);
  double* M   = (double*)take((size_t)ND * ND * 8);
  double* u   = (double*)take((size_t)ND * 8);
  double* t1  = (double*)take((size_t)ND * 8);
  double* wu  = (double*)take((size_t)ND * 8);
  double* t2  = (double*)take((size_t)NB * ND * 8);
  double* vb  = (double*)take((size_t)NB * ND * 8);
  double* W1T   = (double*)take((size_t)NL * NF * ND * 8);   // f64: phase-1 cvt-free
  float*  W2T   = (float*)take((size_t)NL * NF * ND * 4);    // f32: keep L2 working set ~3MB/layer
  double* WqkvT = (double*)take((size_t)NL * 384 * ND * 8);
  double* WoT   = (double*)take((size_t)NL * ND * ND * 8);
  double* WkT   = (double*)take((size_t)ND * ND * 8);
  double* h64T  = (double*)take((size_t)NT * ND * 8);        // [blk8][k][t] h acts (f64 of exact f32)
  float* KMT = qkv;   // alias: qkv (39.3 MB) dead after attention+oln; KMT = 13.1 MB
  float* gum = h;     // alias: h+qkv region (52 MB) >= gum (41 MB); written after k_P

  k_rng<<<1, 64, 0, stream>>>(rng);
  for (int i = 0; i < NL; ++i) {
    k_trd<<<(NF * ND + 255) / 256, 256, 0, stream>>>(W1 + (size_t)i * NF * ND, W1T + (size_t)i * NF * ND, NF, ND);
    k_tr<<<(NF * ND + 255) / 256, 256, 0, stream>>>(W2 + (size_t)i * ND * NF, W2T + (size_t)i * ND * NF, ND, NF);
    k_trd<<<(384 * ND + 255) / 256, 256, 0, stream>>>(Wqkv + (size_t)i * 384 * ND, WqkvT + (size_t)i * 384 * ND, 384, ND);
    k_trd<<<(ND * ND + 255) / 256, 256, 0, stream>>>(Wo + (size_t)i * ND * ND, WoT + (size_t)i * ND * ND, ND, ND);
  }
  k_trd<<<(ND * ND + 255) / 256, 256, 0, stream>>>(Wk, WkT, ND, ND);
  k_embed<<<(NT * ND) / 256, 256, 0, stream>>>(coords, dem, cap, eW, eb, h, dr, h64T);
  for (int i = 0; i < NL; ++i) {
    k_qkv<<<NT / QT, 384, 0, stream>>>(h64T, WqkvT + (size_t)i * 384 * ND, bqkv + (size_t)i * 384, qkv);
    k_attn<<<NB * NH, 256, 0, stream>>>(qkv, att64T);
    k_oln<<<NT / OT, 128, 0, stream>>>(att64T, WoT + (size_t)i * ND * ND, bo + (size_t)i * ND,
                                       ln1g + (size_t)i * ND, ln1b + (size_t)i * ND, h, h64T);
    k_ffn<<<NT / FT, 512, 0, stream>>>(h, h64T, W1T + (size_t)i * NF * ND, b1 + (size_t)i * NF,
                                       W2T + (size_t)i * ND * NF, b2 + (size_t)i * ND,
                                       ln2g + (size_t)i * ND, ln2b + (size_t)i * ND);
  }
  k_gctx<<<NB, 128, 0, stream>>>(h, gctx);
  k_kmat<<<NT / KT, 128, 0, stream>>>(h64T, WkT, kmat);
  k_prep1<<<1, 128, 0, stream>>>(Wctx, bcap, Wcap, bctx, t1, wu);
  k_M<<<ND, 128, 0, stream>>>(Wq, Wctx, M);
  k_u<<<1, 128, 0, stream>>>(Wq, wu, u);
  k_t2<<<NB, 128, 0, stream>>>(Wctx, gctx, t2);
  k_vb<<<NB, 128, 0, stream>>>(Wq, t2, t1, vb);
  k_c01<<<NT / 256, 256, 0, stream>>>(kmat, vb, u, c0, c1);
  k_KM<<<NT / KT, 128, 0, stream>>>(kmat, M, KMT);
  k_P<<<NB * 25, 256, 0, stream>>>(KMT, h, P);
  k_gum<<<(NSTEP * NT + 255) / 256, 256, 0, stream>>>(rng, gum);
  k_decode<<<NB, 64, 0, stream>>>(P, c0, c1, dr, gum, (float*)d_out);
}

// Round 9
// 4742.105 us; speedup vs baseline: 1.6325x; 1.0336x over previous
//
#include <hip/hip_runtime.h>
#include <hip/hip_bf16.h>
#include <stdint.h>
#include <math.h>

#define NB 128
#define NN 200
#define ND 128
#define NH 8
#define DH 16
#define NL 3
#define NF 2048
#define NT (NB * NN)
#define NSTEP 399

// ---------------- Threefry-2x32 (JAX-compatible) ----------------
__host__ __device__ inline void tf2x32(unsigned k0, unsigned k1, unsigned x0, unsigned x1,
                                       unsigned* o0, unsigned* o1) {
  unsigned ks[3] = {k0, k1, k0 ^ k1 ^ 0x1BD11BDAu};
  x0 += ks[0]; x1 += ks[1];
  const unsigned R[2][4] = {{13u, 15u, 26u, 6u}, {17u, 29u, 16u, 24u}};
#pragma unroll
  for (int i = 0; i < 5; ++i) {
#pragma unroll
    for (int j = 0; j < 4; ++j) {
      unsigned r = R[i & 1][j];
      x0 += x1;
      x1 = (x1 << r) | (x1 >> (32u - r));
      x1 ^= x0;
    }
    x0 += ks[(i + 1) % 3];
    x1 += ks[(i + 2) % 3] + (unsigned)(i + 1);
  }
  *o0 = x0; *o1 = x1;
}

// chain is serial (lane 0); leaf s-hashes parallel across the wave
__global__ void k_rng(unsigned* __restrict__ rng) {
  __shared__ unsigned ksh[2 * NSTEP];
  const int l = threadIdx.x;
  if (l == 0) {
    unsigned k0 = 0u, k1 = 42u;
    for (int t = 0; t < NSTEP; ++t) {
      ksh[2 * t] = k0; ksh[2 * t + 1] = k1;
      unsigned a0, a1;
      tf2x32(k0, k1, 0u, 0u, &a0, &a1);
      k0 = a0; k1 = a1;
    }
  }
  __syncthreads();
  for (int t = l; t < NSTEP; t += 64) {
    unsigned s0, s1;
    tf2x32(ksh[2 * t], ksh[2 * t + 1], 0u, 1u, &s0, &s1);
    rng[2 * t] = s0; rng[2 * t + 1] = s1;
  }
}

__global__ __launch_bounds__(256) void k_gum(const unsigned* __restrict__ rng, float* __restrict__ gum) {
  int idx = blockIdx.x * 256 + threadIdx.x;
  if (idx >= NSTEP * NT) return;
  int t = idx / NT, j = idx - t * NT;
  unsigned o0, o1;
  tf2x32(rng[2 * t], rng[2 * t + 1], 0u, (unsigned)j, &o0, &o1);
  unsigned bits = o0 ^ o1;
  float u01 = __uint_as_float((bits >> 9) | 0x3f800000u) - 1.0f;
  float uu = fmaxf(1.17549435082228751e-38f, u01);
  gum[idx] = (float)(-log(-log((double)uu)));
}

// ---------------- fused weight transposes: ONE launch, element math == k_tr/k_trd -------
#define W1SEG (NL * NF * ND)
#define W2SEG (NL * ND * NF)
#define WQSEG (NL * 384 * ND)
#define WOSEG (NL * ND * ND)
#define WKSEG (ND * ND)
#define TRTOT (W1SEG + W2SEG + WQSEG + WOSEG + WKSEG)
__global__ __launch_bounds__(256) void k_trall(const float* __restrict__ W1, const float* __restrict__ W2,
                                               const float* __restrict__ Wqkv, const float* __restrict__ Wo,
                                               const float* __restrict__ Wk,
                                               double* __restrict__ W1T, float* __restrict__ W2T,
                                               double* __restrict__ WqkvT, double* __restrict__ WoT,
                                               double* __restrict__ WkT) {
  int i = blockIdx.x * 256 + threadIdx.x;
  if (i < W1SEG) {                       // R=NF, C=ND, f32->f64
    int L = i / (NF * ND), il = i - L * (NF * ND);
    int c = il / NF, r = il - c * NF;
    W1T[i] = (double)W1[(size_t)L * NF * ND + (size_t)r * ND + c];
    return;
  }
  i -= W1SEG;
  if (i < W2SEG) {                       // R=ND, C=NF, f32->f32
    int L = i / (ND * NF), il = i - L * (ND * NF);
    int c = il / ND, r = il - c * ND;
    W2T[i] = W2[(size_t)L * ND * NF + (size_t)r * NF + c];
    return;
  }
  i -= W2SEG;
  if (i < WQSEG) {                       // R=384, C=ND, f32->f64
    int L = i / (384 * ND), il = i - L * (384 * ND);
    int c = il / 384, r = il - c * 384;
    WqkvT[i] = (double)Wqkv[(size_t)L * 384 * ND + (size_t)r * ND + c];
    return;
  }
  i -= WQSEG;
  if (i < WOSEG) {                       // R=ND, C=ND, f32->f64
    int L = i / (ND * ND), il = i - L * (ND * ND);
    int c = il / ND, r = il - c * ND;
    WoT[i] = (double)Wo[(size_t)L * ND * ND + (size_t)r * ND + c];
    return;
  }
  i -= WOSEG;
  if (i < WKSEG) {                       // R=ND, C=ND, f32->f64
    int c = i / ND, r = i - c * ND;
    WkT[i] = (double)Wk[(size_t)r * ND + c];
    return;
  }
}

// ---------------- embed ----------------
__global__ void k_embed(const float* __restrict__ coords, const float* __restrict__ dem,
                        const float* __restrict__ cap, const float* __restrict__ eW,
                        const float* __restrict__ eb, float* __restrict__ h, float* __restrict__ dr) {
  int gid = blockIdx.x * blockDim.x + threadIdx.x;
  int t = gid >> 7, d = gid & 127;
  int b = t / NN;
  float drv = dem[t] / cap[b];
  double acc = (double)eW[d * 3] * (double)coords[2 * t]
             + (double)eW[d * 3 + 1] * (double)coords[2 * t + 1]
             + (double)eW[d * 3 + 2] * (double)drv;
  h[gid] = (float)acc + eb[d];
  if (d == 0) dr[t] = drv;
}

// ---------------- qkv: 8 tokens/block, f64 weights (L2-resident, 393 KB) ----------------
#define QT 8
__global__ __launch_bounds__(384) void k_qkv(const float* __restrict__ h, const double* __restrict__ WT,
                                             const float* __restrict__ bias, float* __restrict__ qkv) {
  const int t0 = blockIdx.x * QT, j = threadIdx.x;
  __shared__ double hsh[ND][QT];
  for (int idx = j; idx < ND * QT; idx += 384) {
    int t = idx & 7, k = idx >> 3;
    hsh[k][t] = (double)h[(size_t)(t0 + t) * ND + k];
  }
  __syncthreads();
  double acc[QT];
#pragma unroll
  for (int t = 0; t < QT; ++t) acc[t] = 0.0;
  for (int k = 0; k < ND; ++k) {
    double w = WT[(size_t)k * 384 + j];
#pragma unroll
    for (int t = 0; t < QT; ++t) acc[t] += w * hsh[k][t];
  }
  float bv = bias[j];
#pragma unroll
  for (int t = 0; t < QT; ++t)
    qkv[(size_t)(t0 + t) * 384 + j] = (float)acc[t] + bv;
}

// ---------------- attention: wave-per-qn, ONE barrier (R6 exact) ----------------
__global__ __launch_bounds__(256) void k_attn(const float* __restrict__ qkv, float* __restrict__ att) {
  const int b = blockIdx.x / NH, hh = blockIdx.x % NH, tid = threadIdx.x;
  const int lane = tid & 63, w = tid >> 6;
  __shared__ float qsh[NN][DH + 1];
  __shared__ float ksh[NN][DH + 1];
  __shared__ float vsh[NN][DH + 1];
  __shared__ float ashw[4][NN + 8];
  for (int idx = tid; idx < NN * DH; idx += 256) {
    int n = idx / DH, d2 = idx % DH;
    size_t base = (size_t)(b * NN + n) * 384 + hh * DH + d2;
    qsh[n][d2] = qkv[base];
    ksh[n][d2] = qkv[base + ND];
    vsh[n][d2] = qkv[base + 2 * ND];
  }
  __syncthreads();
  const int dd = lane & 15, q4 = lane >> 4;
  for (int qn = w; qn < NN; qn += 4) {
    double qv[DH];
#pragma unroll
    for (int d = 0; d < DH; ++d) qv[d] = (double)qsh[qn][d];
    float sf[4];
#pragma unroll
    for (int s = 0; s < 4; ++s) {
      int n = lane + 64 * s;
      if (n < NN) {
        double a = 0.0;
#pragma unroll
        for (int d = 0; d < DH; ++d) a += qv[d] * (double)ksh[n][d];
        sf[s] = (float)a / 4.0f;
      } else sf[s] = -3.0e38f;
    }
    float m = fmaxf(fmaxf(sf[0], sf[1]), fmaxf(sf[2], sf[3]));
    for (int off = 1; off < 64; off <<= 1) m = fmaxf(m, __shfl_xor(m, off, 64));
    double e[4];
    double esum = 0.0;
#pragma unroll
    for (int s = 0; s < 4; ++s) {
      int n = lane + 64 * s;
      e[s] = (n < NN) ? exp((double)(sf[s] - m)) : 0.0;
      esum += e[s];
    }
    for (int off = 1; off < 64; off <<= 1) esum += __shfl_xor(esum, off, 64);
#pragma unroll
    for (int s = 0; s < 4; ++s) {
      int n = lane + 64 * s;
      if (n < NN) ashw[w][n] = (float)(e[s] / esum);
    }
    double o = 0.0;
    for (int i = 0; i < 50; ++i) {
      int n = q4 * 50 + i;
      o += (double)ashw[w][n] * (double)vsh[n][dd];
    }
    o += __shfl_xor(o, 16, 64);
    o += __shfl_xor(o, 32, 64);
    if (lane < DH)
      att[(size_t)(b * NN + qn) * ND + hh * DH + lane] = (float)o;
  }
}

// ---------------- o-proj + residual + LN1; OT=8, coalesced h64T write -------------------
// Per-(t,d) chains identical to the OT=4 version (ascending k; same LN formulas).
// Thread d writes its 8 consecutive doubles -> 64B/lane coalesced h64T store.
#define OT 8
__global__ __launch_bounds__(128) void k_oln(const float* __restrict__ att, const double* __restrict__ WoT,
                                             const float* __restrict__ bo, const float* __restrict__ g,
                                             const float* __restrict__ bb, const float* __restrict__ h,
                                             double* __restrict__ h64T) {
  const int t0 = blockIdx.x * OT, d = threadIdx.x;
  __shared__ double ash[ND][OT];
  __shared__ float xsh[OT][ND];
  __shared__ float mred[OT], sred[OT];
  for (int idx = d; idx < ND * OT; idx += 128) {
    int t = idx & 7, k = idx >> 3;
    ash[k][t] = (double)att[(size_t)(t0 + t) * ND + k];
  }
  __syncthreads();
  double acc[OT];
#pragma unroll
  for (int t = 0; t < OT; ++t) acc[t] = 0.0;
  for (int k = 0; k < ND; ++k) {
    double w = WoT[(size_t)k * ND + d];
#pragma unroll
    for (int t = 0; t < OT; ++t) acc[t] += w * ash[k][t];
  }
  float bv = bo[d];
#pragma unroll
  for (int t = 0; t < OT; ++t) {
    float o = (float)acc[t] + bv;
    xsh[t][d] = h[(size_t)(t0 + t) * ND + d] + o;
  }
  __syncthreads();
  if (d < OT) {
    double sv = 0.0;
    for (int k = 0; k < ND; ++k) sv += (double)xsh[d][k];
    float m = (float)(sv / 128.0);
    double sq = 0.0;
    for (int k = 0; k < ND; ++k) { float tf = xsh[d][k] - m; sq += (double)tf * (double)tf; }
    mred[d] = m;
    sred[d] = sqrtf((float)(sq / 128.0) + 1e-5f);
  }
  __syncthreads();
  const size_t blk8 = (size_t)blockIdx.x;
#pragma unroll
  for (int t = 0; t < OT; ++t) {
    float tf = xsh[t][d] - mred[t];
    float hv = tf / sred[t] * g[d] + bb[d];
    h64T[blk8 * 1024 + (size_t)d * 8 + t] = (double)hv;  // exact f32 value, coalesced
  }
}

// ---------------- FFN (R6 exact): h from h64T global uniform; W2T f32 -------------------
#define FT 8
__global__ __launch_bounds__(512, 4) void k_ffn(float* __restrict__ h, const double* __restrict__ h64T,
                                                const double* __restrict__ W1T, const float* __restrict__ b1,
                                                const float* __restrict__ W2T, const float* __restrict__ b2,
                                                const float* __restrict__ g, const float* __restrict__ bb) {
  const int tid = threadIdx.x;
  const int t0 = blockIdx.x * FT;
  const double* hp = h64T + (size_t)blockIdx.x * 1024;   // [k][t] for this 8-token block
  __shared__ double red_raw[NF * FT / 2];  // 64 KB: f32 acts [j][8] | f64 reduction (8192)
  __shared__ float xsh[FT][ND];            // 4 KB
  __shared__ float mred[FT], sred[FT];
  float* fsh32 = (float*)red_raw;          // [j][t], row = 32 B
  // ---- phase 1: f = relu(h @ W1^T + b1); j/thread=4, ascending-k chains ----
  {
    const int j0 = tid * 4;
    double acc[4][FT];
#pragma unroll
    for (int a = 0; a < 4; ++a)
#pragma unroll
      for (int t = 0; t < FT; ++t) acc[a][t] = 0.0;
    const double* wrow = W1T + j0;
    for (int k = 0; k < ND; ++k) {
      double2 wa = *(const double2*)(wrow + (size_t)k * NF);
      double2 wb = *(const double2*)(wrow + (size_t)k * NF + 2);
      double wd[4] = {wa.x, wa.y, wb.x, wb.y};
      const double* hr = hp + k * 8;       // lane-invariant address
#pragma unroll
      for (int p = 0; p < 4; ++p) {
        double2 hv = *(const double2*)(hr + 2 * p);
#pragma unroll
        for (int a = 0; a < 4; ++a) {
          acc[a][2 * p] += wd[a] * hv.x;
          acc[a][2 * p + 1] += wd[a] * hv.y;
        }
      }
    }
#pragma unroll
    for (int a = 0; a < 4; ++a) {
      float bv = b1[j0 + a];
#pragma unroll
      for (int t = 0; t < FT; ++t) {
        float f = (float)acc[a][t] + bv;   // f32 round at tensor boundary (exact)
        fsh32[(size_t)(j0 + a) * FT + t] = fmaxf(f, 0.0f);
      }
    }
  }
  __syncthreads();
  // ---- phase 2: acc2 += f @ W2^T; rotated-j chains ----
  const int jg = tid >> 6;                 // wave id = jg chunk (0..7)
  const int lane = tid & 63;
  const int th = lane >> 5;                // token-half (0: t=0..3, 1: t=4..7)
  const int dlo = lane & 31, d0 = dlo << 2;
  double acc2[4][4];
#pragma unroll
  for (int a = 0; a < 4; ++a)
#pragma unroll
    for (int t = 0; t < 4; ++t) acc2[a][t] = 0.0;
  for (int c = 0; c < 2; ++c) {
    for (int i = 0; i < 128; ++i) {
      int jj = (jg << 7) | ((i + jg) & 127);
      int j = (c << 10) | jj;
      float4 wv = *(const float4*)(W2T + (size_t)j * ND + d0);
      float4 fq = *(const float4*)(fsh32 + (size_t)j * FT + th * 4);
      double fv[4] = {(double)fq.x, (double)fq.y, (double)fq.z, (double)fq.w};
      double wd[4] = {(double)wv.x, (double)wv.y, (double)wv.z, (double)wv.w};
#pragma unroll
      for (int a = 0; a < 4; ++a)
#pragma unroll
        for (int t = 0; t < 4; ++t) acc2[a][t] += wd[a] * fv[t];
    }
  }
  __syncthreads();   // act reads done; safe to overwrite as f64 reduction scratch
  // ---- reduction: red[(jg*8 + t)][d]; per-(t,d) partial order jg2 = 0..7 ascending ----
  double* red = red_raw;
#pragma unroll
  for (int a = 0; a < 4; ++a)
#pragma unroll
    for (int t = 0; t < 4; ++t)
      red[((jg * 8 + th * 4 + t) << 7) + d0 + a] = acc2[a][t];
  __syncthreads();
  for (int idx = tid; idx < ND * FT; idx += 512) {
    int t = idx >> 7, d = idx & 127;
    double s = 0.0;
#pragma unroll
    for (int jg2 = 0; jg2 < 8; ++jg2) s += red[((jg2 * 8 + t) << 7) + d];
    float o = (float)s + b2[d];
    float hres = (float)hp[(size_t)d * 8 + t];   // exact f32 value
    xsh[t][d] = hres + o;
  }
  __syncthreads();
  if (tid < FT) {
    double sv = 0.0;
    for (int d = 0; d < ND; ++d) sv += (double)xsh[tid][d];
    float m = (float)(sv / 128.0);
    double sq = 0.0;
    for (int d = 0; d < ND; ++d) { float tf = xsh[tid][d] - m; sq += (double)tf * (double)tf; }
    mred[tid] = m;
    sred[tid] = sqrtf((float)(sq / 128.0) + 1e-5f);
  }
  __syncthreads();
  for (int idx = tid; idx < ND * FT; idx += 512) {
    int d = idx & 127, t = idx >> 7;
    float tf = xsh[t][d] - mred[t];
    h[(size_t)(t0 + t) * ND + d] = tf / sred[t] * g[d] + bb[d];
  }
}

// ---------------- decode precompute ----------------
__global__ __launch_bounds__(128) void k_gctx(const float* __restrict__ h, float* __restrict__ gctx) {
  int b = blockIdx.x, d = threadIdx.x;
  double acc = 0.0;
  for (int n = 0; n < NN; ++n) acc += (double)h[(size_t)(b * NN + n) * ND + d];
  gctx[b * ND + d] = (float)(acc / 200.0);
}

#define KT 8
__global__ __launch_bounds__(128) void k_kmat(const float* __restrict__ h, const double* __restrict__ WkT,
                                              float* __restrict__ kmat) {
  const int t0 = blockIdx.x * KT, d = threadIdx.x;
  __shared__ double hsh[ND][KT];
  for (int idx = d; idx < ND * KT; idx += 128) {
    int t = idx & 7, k = idx >> 3;
    hsh[k][t] = (double)h[(size_t)(t0 + t) * ND + k];
  }
  __syncthreads();
  double acc[KT];
#pragma unroll
  for (int t = 0; t < KT; ++t) acc[t] = 0.0;
  for (int k = 0; k < ND; ++k) {
    double w = WkT[(size_t)k * ND + d];
#pragma unroll
    for (int t = 0; t < KT; ++t) acc[t] += w * hsh[k][t];
  }
#pragma unroll
  for (int t = 0; t < KT; ++t)
    kmat[(size_t)(t0 + t) * ND + d] = (float)acc[t];
}

__global__ __launch_bounds__(128) void k_prep1(const float* __restrict__ Wctx, const float* __restrict__ bcap,
                                               const float* __restrict__ Wcap, const float* __restrict__ bctx,
                                               double* __restrict__ t1, double* __restrict__ wu) {
  int k = threadIdx.x;
  double a = 0.0, c = 0.0;
  for (int m = 0; m < ND; ++m) {
    double wc = (double)Wctx[(size_t)k * 384 + 256 + m];
    a += wc * (double)bcap[m];
    c += wc * (double)Wcap[m];
  }
  t1[k] = a + (double)bctx[k];
  wu[k] = c;
}

__global__ __launch_bounds__(128) void k_M(const float* __restrict__ Wq, const float* __restrict__ Wctx,
                                           double* __restrict__ M) {
  int d = blockIdx.x, j = threadIdx.x;
  double acc = 0.0;
  for (int k = 0; k < ND; ++k)
    acc += (double)Wq[(size_t)d * ND + k] * (double)Wctx[(size_t)k * 384 + j];
  M[(size_t)d * ND + j] = acc;
}

__global__ __launch_bounds__(128) void k_u(const float* __restrict__ Wq, const double* __restrict__ wu,
                                           double* __restrict__ u) {
  int d = threadIdx.x;
  double acc = 0.0;
  for (int k = 0; k < ND; ++k) acc += (double)Wq[(size_t)d * ND + k] * wu[k];
  u[d] = acc;
}

__global__ __launch_bounds__(128) void k_t2(const float* __restrict__ Wctx, const float* __restrict__ gctx,
                                            double* __restrict__ t2) {
  int b = blockIdx.x, k = threadIdx.x;
  double acc = 0.0;
  for (int m = 0; m < ND; ++m)
    acc += (double)Wctx[(size_t)k * 384 + 128 + m] * (double)gctx[b * ND + m];
  t2[(size_t)b * ND + k] = acc;
}

__global__ __launch_bounds__(128) void k_vb(const float* __restrict__ Wq, const double* __restrict__ t2,
                                            const double* __restrict__ t1, double* __restrict__ vb) {
  int b = blockIdx.x, d = threadIdx.x;
  double acc = 0.0;
  for (int k = 0; k < ND; ++k)
    acc += (double)Wq[(size_t)d * ND + k] * (t2[(size_t)b * ND + k] + t1[k]);
  vb[(size_t)b * ND + d] = acc;
}

__global__ __launch_bounds__(256) void k_c01(const float* __restrict__ kmat, const double* __restrict__ vb,
                                             const double* __restrict__ u, float* __restrict__ c0, float* __restrict__ c1) {
  int t = blockIdx.x * 256 + threadIdx.x;
  if (t >= NT) return;
  int b = t / NN;
  double a0 = 0.0, a1 = 0.0;
  for (int d = 0; d < ND; ++d) {
    double km = (double)kmat[(size_t)t * ND + d];
    a0 += km * vb[(size_t)b * ND + d];
    a1 += km * u[d];
  }
  c0[t] = (float)a0;
  c1[t] = (float)a1;
}

// KM -> transposed store KMT[b][j][n]
__global__ __launch_bounds__(128) void k_KM(const float* __restrict__ kmat, const double* __restrict__ M,
                                            float* __restrict__ KMT) {
  const int t0 = blockIdx.x * KT, j = threadIdx.x;
  const int b = t0 / NN, toff = t0 % NN;
  __shared__ double ksh[ND][KT];
  for (int idx = j; idx < ND * KT; idx += 128) {
    int t = idx & 7, k = idx >> 3;
    ksh[k][t] = (double)kmat[(size_t)(t0 + t) * ND + k];
  }
  __syncthreads();
  double acc[KT];
#pragma unroll
  for (int t = 0; t < KT; ++t) acc[t] = 0.0;
  for (int d = 0; d < ND; ++d) {
    double m = M[(size_t)d * ND + j];
#pragma unroll
    for (int t = 0; t < KT; ++t) acc[t] += ksh[d][t] * m;
  }
#pragma unroll
  for (int t = 0; t < KT; ++t)
    KMT[(size_t)b * ND * NN + (size_t)j * NN + toff + t] = (float)acc[t];
}

// P[b][c][n]: coalesced KMT reads; 8 acc chains; ascending-j order
#define PC 8
__global__ __launch_bounds__(256) void k_P(const float* __restrict__ KMT, const float* __restrict__ h,
                                           float* __restrict__ P) {
  const int blk = blockIdx.x;
  const int b = blk / 25, c0 = (blk % 25) * PC;
  const int tid = threadIdx.x;
  __shared__ double h8[ND][PC];
  for (int idx = tid; idx < ND * PC; idx += 256) {
    int t = idx & 7, j = idx >> 3;
    h8[j][t] = (double)h[(size_t)(b * NN + c0 + t) * ND + j];
  }
  __syncthreads();
  if (tid < NN) {
    double acc[PC];
#pragma unroll
    for (int t = 0; t < PC; ++t) acc[t] = 0.0;
    const float* kb = KMT + (size_t)b * ND * NN + tid;
    for (int j = 0; j < ND; ++j) {
      double km = (double)kb[(size_t)j * NN];
#pragma unroll
      for (int t = 0; t < PC; ++t) acc[t] += km * h8[j][t];
    }
#pragma unroll
    for (int t = 0; t < PC; ++t)
      P[(size_t)(b * NN + c0 + t) * NN + tid] = (float)acc[t];
  }
}

// ---------------- decode: one wave / row, P[b] in LDS, gum prefetched ----------------
__global__ __launch_bounds__(64) void k_decode(const float* __restrict__ P, const float* __restrict__ c0,
                                               const float* __restrict__ c1, const float* __restrict__ dr,
                                               const float* __restrict__ gum, float* __restrict__ out) {
  __shared__ float Psh[NN * NN];  // 156.25 KB
  const int b = blockIdx.x, l = threadIdx.x;
  {
    const float4* src = (const float4*)(P + (size_t)b * NN * NN);
    float4* dst = (float4*)Psh;
    for (int i = l; i < (NN * NN) / 4; i += 64) dst[i] = src[i];
  }
  float drs4[4], c04[4], c14[4];
  int vis4[4];
#pragma unroll
  for (int s = 0; s < 4; ++s) {
    int n = l + 64 * s;
    bool valid = n < NN;
    drs4[s] = valid ? dr[b * NN + n] : 1e9f;
    c04[s] = valid ? c0[b * NN + n] : 0.0f;
    c14[s] = valid ? c1[b * NN + n] : 0.0f;
    vis4[s] = valid ? 0 : 1;
  }
  int cur = 0, done = 0;
  float rem = 1.0f, lpsum = 0.0f;
  if (l == 0) out[(size_t)b * 400] = 0.0f;
  __syncthreads();
  const float SQD = 11.3137084989847603f;
  float gv4[4];
#pragma unroll
  for (int s = 0; s < 4; ++s) {
    int n = l + 64 * s;
    gv4[s] = (n < NN) ? gum[(size_t)0 * NT + b * NN + n] : 0.0f;
  }
  for (int t = 0; t < NSTEP; ++t) {
    float gn4[4];
    if (t + 1 < NSTEP) {
      const float* grow = gum + (size_t)(t + 1) * NT + b * NN;
#pragma unroll
      for (int s = 0; s < 4; ++s) {
        int n = l + 64 * s;
        gn4[s] = (n < NN) ? grow[n] : 0.0f;
      }
    }
    const float* Prow = Psh + cur * NN;
    float Pv4[4];
#pragma unroll
    for (int s = 0; s < 4; ++s) {
      int n = l + 64 * s;
      Pv4[s] = (n < NN) ? Prow[n] : 0.0f;
    }
    bool lf = false, lns = false;
#pragma unroll
    for (int s = 0; s < 4; ++s) {
      int n = l + 64 * s;
      if (n >= 1 && n < NN && !vis4[s]) {
        lns = true;
        if (drs4[s] <= rem) lf = true;
      }
    }
    const int has_feas = (__ballot(lf) != 0ULL);
    const int all_served = (__ballot(lns) == 0ULL);
    const bool at_depot = (cur == 0) && !done, not_depot = (cur != 0) && !done;
    const bool depot_mask = (at_depot && has_feas) || (not_depot && has_feas && !all_served);
    float msk[4], sc[4];
#pragma unroll
    for (int s = 0; s < 4; ++s) {
      int n = l + 64 * s;
      if (n < NN) {
        double sd = (double)Pv4[s] + (double)c04[s] + (double)rem * (double)c14[s];
        float logit = (float)sd / SQD;
        bool infn = vis4[s] || (drs4[s] > rem) || (n == 0 && depot_mask);
        msk[s] = infn ? -1e9f : logit;
        sc[s] = msk[s] + gv4[s];
      } else {
        msk[s] = -3.0e38f;
        sc[s] = -3.0e38f;
      }
    }
    float bs = sc[0]; int bn = l; float bmsk = msk[0]; float mx = msk[0];
#pragma unroll
    for (int s = 1; s < 4; ++s) {
      int n = l + 64 * s;
      if (sc[s] > bs) { bs = sc[s]; bn = n; bmsk = msk[s]; }
      mx = fmaxf(mx, msk[s]);
    }
    for (int off = 1; off < 64; off <<= 1) {
      float os = __shfl_xor(bs, off, 64);
      int on = __shfl_xor(bn, off, 64);
      float ob = __shfl_xor(bmsk, off, 64);
      float om = __shfl_xor(mx, off, 64);
      if (os > bs || (os == bs && on < bn)) { bs = os; bn = on; bmsk = ob; }
      mx = fmaxf(mx, om);
    }
    float e = 0.0f;
#pragma unroll
    for (int s = 0; s < 4; ++s) e += expf(msk[s] - mx);
    for (int off = 1; off < 64; off <<= 1) e += __shfl_xor(e, off, 64);
    int sel = bn;
    float slp = (bmsk - mx) - logf(e);
    bool force = (all_served && cur != 0 && !done) || (not_depot && !has_feas) || done;
    if (force) { sel = 0; slp = 0.0f; }
    if (l == 0) out[(size_t)b * 400 + 1 + t] = (float)sel;
    lpsum += slp;
    bool isd = (sel == 0);
    float cand = drs4[sel >> 6];
    float take = __shfl(cand, sel & 63, 64);
    float nr = isd ? 1.0f : (rem - take);
    rem = fminf(fmaxf(nr, 0.0f), 1.0f);
    if (!isd && (sel & 63) == l) vis4[sel >> 6] = 1;
    if (all_served && sel == 0) done = 1;
    cur = sel;
#pragma unroll
    for (int s = 0; s < 4; ++s) gv4[s] = gn4[s];
  }
  if (l == 0) out[(size_t)NB * 400 + b] = lpsum;
}

// ---------------- host ----------------
extern "C" void kernel_launch(void* const* d_in, const int* in_sizes, int n_in,
                              void* d_out, int out_size, void* d_ws, size_t ws_size,
                              hipStream_t stream) {
  (void)in_sizes; (void)n_in; (void)out_size; (void)ws_size;
  const float* coords = (const float*)d_in[0];
  const float* dem    = (const float*)d_in[1];
  const float* cap    = (const float*)d_in[2];
  const float* eW     = (const float*)d_in[3];
  const float* eb     = (const float*)d_in[4];
  const float* Wqkv   = (const float*)d_in[5];
  const float* bqkv   = (const float*)d_in[6];
  const float* Wo     = (const float*)d_in[7];
  const float* bo     = (const float*)d_in[8];
  const float* W1     = (const float*)d_in[9];
  const float* b1     = (const float*)d_in[10];
  const float* W2     = (const float*)d_in[11];
  const float* b2     = (const float*)d_in[12];
  const float* ln1g   = (const float*)d_in[13];
  const float* ln1b   = (const float*)d_in[14];
  const float* ln2g   = (const float*)d_in[15];
  const float* ln2b   = (const float*)d_in[16];
  const float* Wq     = (const float*)d_in[17];
  const float* Wk     = (const float*)d_in[18];
  const float* Wcap   = (const float*)d_in[19];
  const float* bcap   = (const float*)d_in[20];
  const float* Wctx   = (const float*)d_in[21];
  const float* bctx   = (const float*)d_in[22];

  char* ws = (char*)d_ws;
  size_t off = 0;
  auto take = [&](size_t bytes) -> void* {
    void* p = ws + off;
    off += (bytes + 255) & ~(size_t)255;
    return p;
  };
  float* dr   = (float*)take((size_t)NT * 4);
  float* c0   = (float*)take((size_t)NT * 4);
  float* c1   = (float*)take((size_t)NT * 4);
  float* P    = (float*)take((size_t)NB * NN * NN * 4);
  unsigned* rng = (unsigned*)take((size_t)NSTEP * 2 * 4);
  float* h    = (float*)take((size_t)NT * ND * 4);
  float* qkv  = (float*)take((size_t)NT * 384 * 4);
  float* att  = (float*)take((size_t)NT * ND * 4);
  float* kmat = (float*)take((size_t)NT * ND * 4);
  float* gctx = (float*)take((size_t)NB * ND * 4);
  double* M   = (double*)take((size_t)ND * ND * 8);
  double* u   = (double*)take((size_t)ND * 8);
  double* t1  = (double*)take((size_t)ND * 8);
  double* wu  = (double*)take((size_t)ND * 8);
  double* t2  = (double*)take((size_t)NB * ND * 8);
  double* vb  = (double*)take((size_t)NB * ND * 8);
  double* W1T   = (double*)take((size_t)NL * NF * ND * 8);   // f64: phase-1 cvt-free
  float*  W2T   = (float*)take((size_t)NL * NF * ND * 4);    // f32: L2-friendly phase-2
  double* WqkvT = (double*)take((size_t)NL * 384 * ND * 8);
  double* WoT   = (double*)take((size_t)NL * ND * ND * 8);
  double* WkT   = (double*)take((size_t)ND * ND * 8);
  double* h64T  = (double*)take((size_t)NT * ND * 8);        // [blk8][k][t] post-LN1 acts
  float* KMT = qkv;   // alias: qkv (39.3 MB) dead after attention+oln; KMT = 13.1 MB
  float* gum = h;     // alias: h+qkv region (52 MB) >= gum (41 MB); written after k_P

  k_rng<<<1, 64, 0, stream>>>(rng);
  k_trall<<<(TRTOT + 255) / 256, 256, 0, stream>>>(W1, W2, Wqkv, Wo, Wk, W1T, W2T, WqkvT, WoT, WkT);
  k_embed<<<(NT * ND) / 256, 256, 0, stream>>>(coords, dem, cap, eW, eb, h, dr);
  for (int i = 0; i < NL; ++i) {
    k_qkv<<<NT / QT, 384, 0, stream>>>(h, WqkvT + (size_t)i * 384 * ND, bqkv + (size_t)i * 384, qkv);
    k_attn<<<NB * NH, 256, 0, stream>>>(qkv, att);
    k_oln<<<NT / OT, 128, 0, stream>>>(att, WoT + (size_t)i * ND * ND, bo + (size_t)i * ND,
                                       ln1g + (size_t)i * ND, ln1b + (size_t)i * ND, h, h64T);
    k_ffn<<<NT / FT, 512, 0, stream>>>(h, h64T, W1T + (size_t)i * NF * ND, b1 + (size_t)i * NF,
                                       W2T + (size_t)i * ND * NF, b2 + (size_t)i * ND,
                                       ln2g + (size_t)i * ND, ln2b + (size_t)i * ND);
  }
  k_gctx<<<NB, 128, 0, stream>>>(h, gctx);
  k_kmat<<<NT / KT, 128, 0, stream>>>(h, WkT, kmat);
  k_prep1<<<1, 128, 0, stream>>>(Wctx, bcap, Wcap, bctx, t1, wu);
  k_M<<<ND, 128, 0, stream>>>(Wq, Wctx, M);
  k_u<<<1, 128, 0, stream>>>(Wq, wu, u);
  k_t2<<<NB, 128, 0, stream>>>(Wctx, gctx, t2);
  k_vb<<<NB, 128, 0, stream>>>(Wq, t2, t1, vb);
  k_c01<<<NT / 256, 256, 0, stream>>>(kmat, vb, u, c0, c1);
  k_KM<<<NT / KT, 128, 0, stream>>>(kmat, M, KMT);
  k_P<<<NB * 25, 256, 0, stream>>>(KMT, h, P);
  k_gum<<<(NSTEP * NT + 255) / 256, 256, 0, stream>>>(rng, gum);
  k_decode<<<NB, 64, 0, stream>>>(P, c0, c1, dr, gum, (float*)d_out);
}

// Round 10
// 4576.564 us; speedup vs baseline: 1.6915x; 1.0362x over previous
//
#include <hip/hip_runtime.h>
#include <hip/hip_bf16.h>
#include <stdint.h>
#include <math.h>

#define NB 128
#define NN 200
#define ND 128
#define NH 8
#define DH 16
#define NL 3
#define NF 2048
#define NT (NB * NN)
#define NSTEP 399

// ---------------- Threefry-2x32 (JAX-compatible) ----------------
__host__ __device__ inline void tf2x32(unsigned k0, unsigned k1, unsigned x0, unsigned x1,
                                       unsigned* o0, unsigned* o1) {
  unsigned ks[3] = {k0, k1, k0 ^ k1 ^ 0x1BD11BDAu};
  x0 += ks[0]; x1 += ks[1];
  const unsigned R[2][4] = {{13u, 15u, 26u, 6u}, {17u, 29u, 16u, 24u}};
#pragma unroll
  for (int i = 0; i < 5; ++i) {
#pragma unroll
    for (int j = 0; j < 4; ++j) {
      unsigned r = R[i & 1][j];
      x0 += x1;
      x1 = (x1 << r) | (x1 >> (32u - r));
      x1 ^= x0;
    }
    x0 += ks[(i + 1) % 3];
    x1 += ks[(i + 2) % 3] + (unsigned)(i + 1);
  }
  *o0 = x0; *o1 = x1;
}

// chain is serial (lane 0); leaf s-hashes parallel across the wave
__global__ void k_rng(unsigned* __restrict__ rng) {
  __shared__ unsigned ksh[2 * NSTEP];
  const int l = threadIdx.x;
  if (l == 0) {
    unsigned k0 = 0u, k1 = 42u;
    for (int t = 0; t < NSTEP; ++t) {
      ksh[2 * t] = k0; ksh[2 * t + 1] = k1;
      unsigned a0, a1;
      tf2x32(k0, k1, 0u, 0u, &a0, &a1);
      k0 = a0; k1 = a1;
    }
  }
  __syncthreads();
  for (int t = l; t < NSTEP; t += 64) {
    unsigned s0, s1;
    tf2x32(ksh[2 * t], ksh[2 * t + 1], 0u, 1u, &s0, &s1);
    rng[2 * t] = s0; rng[2 * t + 1] = s1;
  }
}

__global__ __launch_bounds__(256) void k_gum(const unsigned* __restrict__ rng, float* __restrict__ gum) {
  int idx = blockIdx.x * 256 + threadIdx.x;
  if (idx >= NSTEP * NT) return;
  int t = idx / NT, j = idx - t * NT;
  unsigned o0, o1;
  tf2x32(rng[2 * t], rng[2 * t + 1], 0u, (unsigned)j, &o0, &o1);
  unsigned bits = o0 ^ o1;
  float u01 = __uint_as_float((bits >> 9) | 0x3f800000u) - 1.0f;
  float uu = fmaxf(1.17549435082228751e-38f, u01);
  gum[idx] = (float)(-log(-log((double)uu)));
}

// ---------------- fused weight transposes: ONE launch, element math == k_tr/k_trd -------
#define W1SEG (NL * NF * ND)
#define W2SEG (NL * ND * NF)
#define WQSEG (NL * 384 * ND)
#define WOSEG (NL * ND * ND)
#define WKSEG (ND * ND)
#define TRTOT (W1SEG + W2SEG + WQSEG + WOSEG + WKSEG)
__global__ __launch_bounds__(256) void k_trall(const float* __restrict__ W1, const float* __restrict__ W2,
                                               const float* __restrict__ Wqkv, const float* __restrict__ Wo,
                                               const float* __restrict__ Wk,
                                               double* __restrict__ W1T, float* __restrict__ W2T,
                                               double* __restrict__ WqkvT, double* __restrict__ WoT,
                                               double* __restrict__ WkT) {
  int i = blockIdx.x * 256 + threadIdx.x;
  if (i < W1SEG) {                       // R=NF, C=ND, f32->f64
    int L = i / (NF * ND), il = i - L * (NF * ND);
    int c = il / NF, r = il - c * NF;
    W1T[i] = (double)W1[(size_t)L * NF * ND + (size_t)r * ND + c];
    return;
  }
  i -= W1SEG;
  if (i < W2SEG) {                       // R=ND, C=NF, f32->f32
    int L = i / (ND * NF), il = i - L * (ND * NF);
    int c = il / ND, r = il - c * ND;
    W2T[i] = W2[(size_t)L * ND * NF + (size_t)r * NF + c];
    return;
  }
  i -= W2SEG;
  if (i < WQSEG) {                       // R=384, C=ND, f32->f64
    int L = i / (384 * ND), il = i - L * (384 * ND);
    int c = il / 384, r = il - c * 384;
    WqkvT[i] = (double)Wqkv[(size_t)L * 384 * ND + (size_t)r * ND + c];
    return;
  }
  i -= WQSEG;
  if (i < WOSEG) {                       // R=ND, C=ND, f32->f64
    int L = i / (ND * ND), il = i - L * (ND * ND);
    int c = il / ND, r = il - c * ND;
    WoT[i] = (double)Wo[(size_t)L * ND * ND + (size_t)r * ND + c];
    return;
  }
  i -= WOSEG;
  if (i < WKSEG) {                       // R=ND, C=ND, f32->f64
    int c = i / ND, r = i - c * ND;
    WkT[i] = (double)Wk[(size_t)r * ND + c];
    return;
  }
}

// ---------------- embed ----------------
__global__ void k_embed(const float* __restrict__ coords, const float* __restrict__ dem,
                        const float* __restrict__ cap, const float* __restrict__ eW,
                        const float* __restrict__ eb, float* __restrict__ h, float* __restrict__ dr) {
  int gid = blockIdx.x * blockDim.x + threadIdx.x;
  int t = gid >> 7, d = gid & 127;
  int b = t / NN;
  float drv = dem[t] / cap[b];
  double acc = (double)eW[d * 3] * (double)coords[2 * t]
             + (double)eW[d * 3 + 1] * (double)coords[2 * t + 1]
             + (double)eW[d * 3 + 2] * (double)drv;
  h[gid] = (float)acc + eb[d];
  if (d == 0) dr[t] = drv;
}

// ---------------- qkv: 8 tokens/block, f64 weights (L2-resident, 393 KB) ----------------
#define QT 8
__global__ __launch_bounds__(384) void k_qkv(const float* __restrict__ h, const double* __restrict__ WT,
                                             const float* __restrict__ bias, float* __restrict__ qkv) {
  const int t0 = blockIdx.x * QT, j = threadIdx.x;
  __shared__ double hsh[ND][QT];
  for (int idx = j; idx < ND * QT; idx += 384) {
    int t = idx & 7, k = idx >> 3;
    hsh[k][t] = (double)h[(size_t)(t0 + t) * ND + k];
  }
  __syncthreads();
  double acc[QT];
#pragma unroll
  for (int t = 0; t < QT; ++t) acc[t] = 0.0;
  for (int k = 0; k < ND; ++k) {
    double w = WT[(size_t)k * 384 + j];
#pragma unroll
    for (int t = 0; t < QT; ++t) acc[t] += w * hsh[k][t];
  }
  float bv = bias[j];
#pragma unroll
  for (int t = 0; t < QT; ++t)
    qkv[(size_t)(t0 + t) * 384 + j] = (float)acc[t] + bv;
}

// ---------------- attention: vectorized QK reads (b128), pad 17->20 ---------------------
// QK chain content + order unchanged: a += qv[d]*(double)k[d], d = 0..15 ascending.
// Values identical (same f32s, same slots). Softmax/PV/output byte-identical to R6/R9.
#define KP 20   // row pad: 80 B rows -> 16B-aligned float4 reads
__global__ __launch_bounds__(256) void k_attn(const float* __restrict__ qkv, float* __restrict__ att) {
  const int b = blockIdx.x / NH, hh = blockIdx.x % NH, tid = threadIdx.x;
  const int lane = tid & 63, w = tid >> 6;
  __shared__ __align__(16) float qsh[NN][KP];
  __shared__ __align__(16) float ksh[NN][KP];
  __shared__ __align__(16) float vsh[NN][KP];
  __shared__ float ashw[4][NN + 8];
  for (int idx = tid; idx < NN * DH; idx += 256) {
    int n = idx / DH, d2 = idx % DH;
    size_t base = (size_t)(b * NN + n) * 384 + hh * DH + d2;
    qsh[n][d2] = qkv[base];
    ksh[n][d2] = qkv[base + ND];
    vsh[n][d2] = qkv[base + 2 * ND];
  }
  __syncthreads();
  const int dd = lane & 15, q4 = lane >> 4;
  for (int qn = w; qn < NN; qn += 4) {
    double qv[DH];
    {
      const float4* qr = (const float4*)&qsh[qn][0];
      float4 q0 = qr[0], q1 = qr[1], q2 = qr[2], q3 = qr[3];
      float qf[DH] = {q0.x, q0.y, q0.z, q0.w, q1.x, q1.y, q1.z, q1.w,
                      q2.x, q2.y, q2.z, q2.w, q3.x, q3.y, q3.z, q3.w};
#pragma unroll
      for (int d = 0; d < DH; ++d) qv[d] = (double)qf[d];
    }
    float sf[4];
#pragma unroll
    for (int s = 0; s < 4; ++s) {
      int n = lane + 64 * s;
      if (n < NN) {
        const float4* kr = (const float4*)&ksh[n][0];
        float4 k0 = kr[0], k1 = kr[1], k2 = kr[2], k3 = kr[3];
        float kf[DH] = {k0.x, k0.y, k0.z, k0.w, k1.x, k1.y, k1.z, k1.w,
                        k2.x, k2.y, k2.z, k2.w, k3.x, k3.y, k3.z, k3.w};
        double a = 0.0;
#pragma unroll
        for (int d = 0; d < DH; ++d) a += qv[d] * (double)kf[d];
        sf[s] = (float)a / 4.0f;
      } else sf[s] = -3.0e38f;
    }
    float m = fmaxf(fmaxf(sf[0], sf[1]), fmaxf(sf[2], sf[3]));
    for (int off = 1; off < 64; off <<= 1) m = fmaxf(m, __shfl_xor(m, off, 64));
    double e[4];
    double esum = 0.0;
#pragma unroll
    for (int s = 0; s < 4; ++s) {
      int n = lane + 64 * s;
      e[s] = (n < NN) ? exp((double)(sf[s] - m)) : 0.0;
      esum += e[s];
    }
    for (int off = 1; off < 64; off <<= 1) esum += __shfl_xor(esum, off, 64);
#pragma unroll
    for (int s = 0; s < 4; ++s) {
      int n = lane + 64 * s;
      if (n < NN) ashw[w][n] = (float)(e[s] / esum);
    }
    double o = 0.0;
    for (int i = 0; i < 50; ++i) {
      int n = q4 * 50 + i;
      o += (double)ashw[w][n] * (double)vsh[n][dd];
    }
    o += __shfl_xor(o, 16, 64);
    o += __shfl_xor(o, 32, 64);
    if (lane < DH)
      att[(size_t)(b * NN + qn) * ND + hh * DH + lane] = (float)o;
  }
}

// ---------------- o-proj + residual + LN1; OT=8, coalesced h64T write -------------------
#define OT 8
__global__ __launch_bounds__(128) void k_oln(const float* __restrict__ att, const double* __restrict__ WoT,
                                             const float* __restrict__ bo, const float* __restrict__ g,
                                             const float* __restrict__ bb, const float* __restrict__ h,
                                             double* __restrict__ h64T) {
  const int t0 = blockIdx.x * OT, d = threadIdx.x;
  __shared__ double ash[ND][OT];
  __shared__ float xsh[OT][ND];
  __shared__ float mred[OT], sred[OT];
  for (int idx = d; idx < ND * OT; idx += 128) {
    int t = idx & 7, k = idx >> 3;
    ash[k][t] = (double)att[(size_t)(t0 + t) * ND + k];
  }
  __syncthreads();
  double acc[OT];
#pragma unroll
  for (int t = 0; t < OT; ++t) acc[t] = 0.0;
  for (int k = 0; k < ND; ++k) {
    double w = WoT[(size_t)k * ND + d];
#pragma unroll
    for (int t = 0; t < OT; ++t) acc[t] += w * ash[k][t];
  }
  float bv = bo[d];
#pragma unroll
  for (int t = 0; t < OT; ++t) {
    float o = (float)acc[t] + bv;
    xsh[t][d] = h[(size_t)(t0 + t) * ND + d] + o;
  }
  __syncthreads();
  if (d < OT) {
    double sv = 0.0;
    for (int k = 0; k < ND; ++k) sv += (double)xsh[d][k];
    float m = (float)(sv / 128.0);
    double sq = 0.0;
    for (int k = 0; k < ND; ++k) { float tf = xsh[d][k] - m; sq += (double)tf * (double)tf; }
    mred[d] = m;
    sred[d] = sqrtf((float)(sq / 128.0) + 1e-5f);
  }
  __syncthreads();
  const size_t blk8 = (size_t)blockIdx.x;
#pragma unroll
  for (int t = 0; t < OT; ++t) {
    float tf = xsh[t][d] - mred[t];
    float hv = tf / sred[t] * g[d] + bb[d];
    h64T[blk8 * 1024 + (size_t)d * 8 + t] = (double)hv;  // exact f32 value, coalesced
  }
}

// ---------------- FFN (R6 exact): h from h64T global uniform; W2T f32 -------------------
#define FT 8
__global__ __launch_bounds__(512, 4) void k_ffn(float* __restrict__ h, const double* __restrict__ h64T,
                                                const double* __restrict__ W1T, const float* __restrict__ b1,
                                                const float* __restrict__ W2T, const float* __restrict__ b2,
                                                const float* __restrict__ g, const float* __restrict__ bb) {
  const int tid = threadIdx.x;
  const int t0 = blockIdx.x * FT;
  const double* hp = h64T + (size_t)blockIdx.x * 1024;   // [k][t] for this 8-token block
  __shared__ double red_raw[NF * FT / 2];  // 64 KB: f32 acts [j][8] | f64 reduction (8192)
  __shared__ float xsh[FT][ND];            // 4 KB
  __shared__ float mred[FT], sred[FT];
  float* fsh32 = (float*)red_raw;          // [j][t], row = 32 B
  // ---- phase 1: f = relu(h @ W1^T + b1); j/thread=4, ascending-k chains ----
  {
    const int j0 = tid * 4;
    double acc[4][FT];
#pragma unroll
    for (int a = 0; a < 4; ++a)
#pragma unroll
      for (int t = 0; t < FT; ++t) acc[a][t] = 0.0;
    const double* wrow = W1T + j0;
    for (int k = 0; k < ND; ++k) {
      double2 wa = *(const double2*)(wrow + (size_t)k * NF);
      double2 wb = *(const double2*)(wrow + (size_t)k * NF + 2);
      double wd[4] = {wa.x, wa.y, wb.x, wb.y};
      const double* hr = hp + k * 8;       // lane-invariant address
#pragma unroll
      for (int p = 0; p < 4; ++p) {
        double2 hv = *(const double2*)(hr + 2 * p);
#pragma unroll
        for (int a = 0; a < 4; ++a) {
          acc[a][2 * p] += wd[a] * hv.x;
          acc[a][2 * p + 1] += wd[a] * hv.y;
        }
      }
    }
#pragma unroll
    for (int a = 0; a < 4; ++a) {
      float bv = b1[j0 + a];
#pragma unroll
      for (int t = 0; t < FT; ++t) {
        float f = (float)acc[a][t] + bv;   // f32 round at tensor boundary (exact)
        fsh32[(size_t)(j0 + a) * FT + t] = fmaxf(f, 0.0f);
      }
    }
  }
  __syncthreads();
  // ---- phase 2: acc2 += f @ W2^T; rotated-j chains ----
  const int jg = tid >> 6;                 // wave id = jg chunk (0..7)
  const int lane = tid & 63;
  const int th = lane >> 5;                // token-half (0: t=0..3, 1: t=4..7)
  const int dlo = lane & 31, d0 = dlo << 2;
  double acc2[4][4];
#pragma unroll
  for (int a = 0; a < 4; ++a)
#pragma unroll
    for (int t = 0; t < 4; ++t) acc2[a][t] = 0.0;
  for (int c = 0; c < 2; ++c) {
    for (int i = 0; i < 128; ++i) {
      int jj = (jg << 7) | ((i + jg) & 127);
      int j = (c << 10) | jj;
      float4 wv = *(const float4*)(W2T + (size_t)j * ND + d0);
      float4 fq = *(const float4*)(fsh32 + (size_t)j * FT + th * 4);
      double fv[4] = {(double)fq.x, (double)fq.y, (double)fq.z, (double)fq.w};
      double wd[4] = {(double)wv.x, (double)wv.y, (double)wv.z, (double)wv.w};
#pragma unroll
      for (int a = 0; a < 4; ++a)
#pragma unroll
        for (int t = 0; t < 4; ++t) acc2[a][t] += wd[a] * fv[t];
    }
  }
  __syncthreads();   // act reads done; safe to overwrite as f64 reduction scratch
  // ---- reduction: red[(jg*8 + t)][d]; per-(t,d) partial order jg2 = 0..7 ascending ----
  double* red = red_raw;
#pragma unroll
  for (int a = 0; a < 4; ++a)
#pragma unroll
    for (int t = 0; t < 4; ++t)
      red[((jg * 8 + th * 4 + t) << 7) + d0 + a] = acc2[a][t];
  __syncthreads();
  for (int idx = tid; idx < ND * FT; idx += 512) {
    int t = idx >> 7, d = idx & 127;
    double s = 0.0;
#pragma unroll
    for (int jg2 = 0; jg2 < 8; ++jg2) s += red[((jg2 * 8 + t) << 7) + d];
    float o = (float)s + b2[d];
    float hres = (float)hp[(size_t)d * 8 + t];   // exact f32 value
    xsh[t][d] = hres + o;
  }
  __syncthreads();
  if (tid < FT) {
    double sv = 0.0;
    for (int d = 0; d < ND; ++d) sv += (double)xsh[tid][d];
    float m = (float)(sv / 128.0);
    double sq = 0.0;
    for (int d = 0; d < ND; ++d) { float tf = xsh[tid][d] - m; sq += (double)tf * (double)tf; }
    mred[tid] = m;
    sred[tid] = sqrtf((float)(sq / 128.0) + 1e-5f);
  }
  __syncthreads();
  for (int idx = tid; idx < ND * FT; idx += 512) {
    int d = idx & 127, t = idx >> 7;
    float tf = xsh[t][d] - mred[t];
    h[(size_t)(t0 + t) * ND + d] = tf / sred[t] * g[d] + bb[d];
  }
}

// ---------------- decode precompute ----------------
__global__ __launch_bounds__(128) void k_gctx(const float* __restrict__ h, float* __restrict__ gctx) {
  int b = blockIdx.x, d = threadIdx.x;
  double acc = 0.0;
  for (int n = 0; n < NN; ++n) acc += (double)h[(size_t)(b * NN + n) * ND + d];
  gctx[b * ND + d] = (float)(acc / 200.0);
}

#define KT 8
__global__ __launch_bounds__(128) void k_kmat(const float* __restrict__ h, const double* __restrict__ WkT,
                                              float* __restrict__ kmat) {
  const int t0 = blockIdx.x * KT, d = threadIdx.x;
  __shared__ double hsh[ND][KT];
  for (int idx = d; idx < ND * KT; idx += 128) {
    int t = idx & 7, k = idx >> 3;
    hsh[k][t] = (double)h[(size_t)(t0 + t) * ND + k];
  }
  __syncthreads();
  double acc[KT];
#pragma unroll
  for (int t = 0; t < KT; ++t) acc[t] = 0.0;
  for (int k = 0; k < ND; ++k) {
    double w = WkT[(size_t)k * ND + d];
#pragma unroll
    for (int t = 0; t < KT; ++t) acc[t] += w * hsh[k][t];
  }
#pragma unroll
  for (int t = 0; t < KT; ++t)
    kmat[(size_t)(t0 + t) * ND + d] = (float)acc[t];
}

__global__ __launch_bounds__(128) void k_prep1(const float* __restrict__ Wctx, const float* __restrict__ bcap,
                                               const float* __restrict__ Wcap, const float* __restrict__ bctx,
                                               double* __restrict__ t1, double* __restrict__ wu) {
  int k = threadIdx.x;
  double a = 0.0, c = 0.0;
  for (int m = 0; m < ND; ++m) {
    double wc = (double)Wctx[(size_t)k * 384 + 256 + m];
    a += wc * (double)bcap[m];
    c += wc * (double)Wcap[m];
  }
  t1[k] = a + (double)bctx[k];
  wu[k] = c;
}

__global__ __launch_bounds__(128) void k_M(const float* __restrict__ Wq, const float* __restrict__ Wctx,
                                           double* __restrict__ M) {
  int d = blockIdx.x, j = threadIdx.x;
  double acc = 0.0;
  for (int k = 0; k < ND; ++k)
    acc += (double)Wq[(size_t)d * ND + k] * (double)Wctx[(size_t)k * 384 + j];
  M[(size_t)d * ND + j] = acc;
}

__global__ __launch_bounds__(128) void k_u(const float* __restrict__ Wq, const double* __restrict__ wu,
                                           double* __restrict__ u) {
  int d = threadIdx.x;
  double acc = 0.0;
  for (int k = 0; k < ND; ++k) acc += (double)Wq[(size_t)d * ND + k] * wu[k];
  u[d] = acc;
}

__global__ __launch_bounds__(128) void k_t2(const float* __restrict__ Wctx, const float* __restrict__ gctx,
                                            double* __restrict__ t2) {
  int b = blockIdx.x, k = threadIdx.x;
  double acc = 0.0;
  for (int m = 0; m < ND; ++m)
    acc += (double)Wctx[(size_t)k * 384 + 128 + m] * (double)gctx[b * ND + m];
  t2[(size_t)b * ND + k] = acc;
}

__global__ __launch_bounds__(128) void k_vb(const float* __restrict__ Wq, const double* __restrict__ t2,
                                            const double* __restrict__ t1, double* __restrict__ vb) {
  int b = blockIdx.x, d = threadIdx.x;
  double acc = 0.0;
  for (int k = 0; k < ND; ++k)
    acc += (double)Wq[(size_t)d * ND + k] * (t2[(size_t)b * ND + k] + t1[k]);
  vb[(size_t)b * ND + d] = acc;
}

__global__ __launch_bounds__(256) void k_c01(const float* __restrict__ kmat, const double* __restrict__ vb,
                                             const double* __restrict__ u, float* __restrict__ c0, float* __restrict__ c1) {
  int t = blockIdx.x * 256 + threadIdx.x;
  if (t >= NT) return;
  int b = t / NN;
  double a0 = 0.0, a1 = 0.0;
  for (int d = 0; d < ND; ++d) {
    double km = (double)kmat[(size_t)t * ND + d];
    a0 += km * vb[(size_t)b * ND + d];
    a1 += km * u[d];
  }
  c0[t] = (float)a0;
  c1[t] = (float)a1;
}

// KM -> transposed store KMT[b][j][n]
__global__ __launch_bounds__(128) void k_KM(const float* __restrict__ kmat, const double* __restrict__ M,
                                            float* __restrict__ KMT) {
  const int t0 = blockIdx.x * KT, j = threadIdx.x;
  const int b = t0 / NN, toff = t0 % NN;
  __shared__ double ksh[ND][KT];
  for (int idx = j; idx < ND * KT; idx += 128) {
    int t = idx & 7, k = idx >> 3;
    ksh[k][t] = (double)kmat[(size_t)(t0 + t) * ND + k];
  }
  __syncthreads();
  double acc[KT];
#pragma unroll
  for (int t = 0; t < KT; ++t) acc[t] = 0.0;
  for (int d = 0; d < ND; ++d) {
    double m = M[(size_t)d * ND + j];
#pragma unroll
    for (int t = 0; t < KT; ++t) acc[t] += ksh[d][t] * m;
  }
#pragma unroll
  for (int t = 0; t < KT; ++t)
    KMT[(size_t)b * ND * NN + (size_t)j * NN + toff + t] = (float)acc[t];
}

// P[b][c][n]: coalesced KMT reads; 8 acc chains; ascending-j order
#define PC 8
__global__ __launch_bounds__(256) void k_P(const float* __restrict__ KMT, const float* __restrict__ h,
                                           float* __restrict__ P) {
  const int blk = blockIdx.x;
  const int b = blk / 25, c0 = (blk % 25) * PC;
  const int tid = threadIdx.x;
  __shared__ double h8[ND][PC];
  for (int idx = tid; idx < ND * PC; idx += 256) {
    int t = idx & 7, j = idx >> 3;
    h8[j][t] = (double)h[(size_t)(b * NN + c0 + t) * ND + j];
  }
  __syncthreads();
  if (tid < NN) {
    double acc[PC];
#pragma unroll
    for (int t = 0; t < PC; ++t) acc[t] = 0.0;
    const float* kb = KMT + (size_t)b * ND * NN + tid;
    for (int j = 0; j < ND; ++j) {
      double km = (double)kb[(size_t)j * NN];
#pragma unroll
      for (int t = 0; t < PC; ++t) acc[t] += km * h8[j][t];
    }
#pragma unroll
    for (int t = 0; t < PC; ++t)
      P[(size_t)(b * NN + c0 + t) * NN + tid] = (float)acc[t];
  }
}

// ---------------- decode: one wave / row, P[b] in LDS, gum prefetched ----------------
__global__ __launch_bounds__(64) void k_decode(const float* __restrict__ P, const float* __restrict__ c0,
                                               const float* __restrict__ c1, const float* __restrict__ dr,
                                               const float* __restrict__ gum, float* __restrict__ out) {
  __shared__ float Psh[NN * NN];  // 156.25 KB
  const int b = blockIdx.x, l = threadIdx.x;
  {
    const float4* src = (const float4*)(P + (size_t)b * NN * NN);
    float4* dst = (float4*)Psh;
    for (int i = l; i < (NN * NN) / 4; i += 64) dst[i] = src[i];
  }
  float drs4[4], c04[4], c14[4];
  int vis4[4];
#pragma unroll
  for (int s = 0; s < 4; ++s) {
    int n = l + 64 * s;
    bool valid = n < NN;
    drs4[s] = valid ? dr[b * NN + n] : 1e9f;
    c04[s] = valid ? c0[b * NN + n] : 0.0f;
    c14[s] = valid ? c1[b * NN + n] : 0.0f;
    vis4[s] = valid ? 0 : 1;
  }
  int cur = 0, done = 0;
  float rem = 1.0f, lpsum = 0.0f;
  if (l == 0) out[(size_t)b * 400] = 0.0f;
  __syncthreads();
  const float SQD = 11.3137084989847603f;
  float gv4[4];
#pragma unroll
  for (int s = 0; s < 4; ++s) {
    int n = l + 64 * s;
    gv4[s] = (n < NN) ? gum[(size_t)0 * NT + b * NN + n] : 0.0f;
  }
  for (int t = 0; t < NSTEP; ++t) {
    float gn4[4];
    if (t + 1 < NSTEP) {
      const float* grow = gum + (size_t)(t + 1) * NT + b * NN;
#pragma unroll
      for (int s = 0; s < 4; ++s) {
        int n = l + 64 * s;
        gn4[s] = (n < NN) ? grow[n] : 0.0f;
      }
    }
    const float* Prow = Psh + cur * NN;
    float Pv4[4];
#pragma unroll
    for (int s = 0; s < 4; ++s) {
      int n = l + 64 * s;
      Pv4[s] = (n < NN) ? Prow[n] : 0.0f;
    }
    bool lf = false, lns = false;
#pragma unroll
    for (int s = 0; s < 4; ++s) {
      int n = l + 64 * s;
      if (n >= 1 && n < NN && !vis4[s]) {
        lns = true;
        if (drs4[s] <= rem) lf = true;
      }
    }
    const int has_feas = (__ballot(lf) != 0ULL);
    const int all_served = (__ballot(lns) == 0ULL);
    const bool at_depot = (cur == 0) && !done, not_depot = (cur != 0) && !done;
    const bool depot_mask = (at_depot && has_feas) || (not_depot && has_feas && !all_served);
    float msk[4], sc[4];
#pragma unroll
    for (int s = 0; s < 4; ++s) {
      int n = l + 64 * s;
      if (n < NN) {
        double sd = (double)Pv4[s] + (double)c04[s] + (double)rem * (double)c14[s];
        float logit = (float)sd / SQD;
        bool infn = vis4[s] || (drs4[s] > rem) || (n == 0 && depot_mask);
        msk[s] = infn ? -1e9f : logit;
        sc[s] = msk[s] + gv4[s];
      } else {
        msk[s] = -3.0e38f;
        sc[s] = -3.0e38f;
      }
    }
    float bs = sc[0]; int bn = l; float bmsk = msk[0]; float mx = msk[0];
#pragma unroll
    for (int s = 1; s < 4; ++s) {
      int n = l + 64 * s;
      if (sc[s] > bs) { bs = sc[s]; bn = n; bmsk = msk[s]; }
      mx = fmaxf(mx, msk[s]);
    }
    for (int off = 1; off < 64; off <<= 1) {
      float os = __shfl_xor(bs, off, 64);
      int on = __shfl_xor(bn, off, 64);
      float ob = __shfl_xor(bmsk, off, 64);
      float om = __shfl_xor(mx, off, 64);
      if (os > bs || (os == bs && on < bn)) { bs = os; bn = on; bmsk = ob; }
      mx = fmaxf(mx, om);
    }
    float e = 0.0f;
#pragma unroll
    for (int s = 0; s < 4; ++s) e += expf(msk[s] - mx);
    for (int off = 1; off < 64; off <<= 1) e += __shfl_xor(e, off, 64);
    int sel = bn;
    float slp = (bmsk - mx) - logf(e);
    bool force = (all_served && cur != 0 && !done) || (not_depot && !has_feas) || done;
    if (force) { sel = 0; slp = 0.0f; }
    if (l == 0) out[(size_t)b * 400 + 1 + t] = (float)sel;
    lpsum += slp;
    bool isd = (sel == 0);
    float cand = drs4[sel >> 6];
    float take = __shfl(cand, sel & 63, 64);
    float nr = isd ? 1.0f : (rem - take);
    rem = fminf(fmaxf(nr, 0.0f), 1.0f);
    if (!isd && (sel & 63) == l) vis4[sel >> 6] = 1;
    if (all_served && sel == 0) done = 1;
    cur = sel;
#pragma unroll
    for (int s = 0; s < 4; ++s) gv4[s] = gn4[s];
  }
  if (l == 0) out[(size_t)NB * 400 + b] = lpsum;
}

// ---------------- host ----------------
extern "C" void kernel_launch(void* const* d_in, const int* in_sizes, int n_in,
                              void* d_out, int out_size, void* d_ws, size_t ws_size,
                              hipStream_t stream) {
  (void)in_sizes; (void)n_in; (void)out_size; (void)ws_size;
  const float* coords = (const float*)d_in[0];
  const float* dem    = (const float*)d_in[1];
  const float* cap    = (const float*)d_in[2];
  const float* eW     = (const float*)d_in[3];
  const float* eb     = (const float*)d_in[4];
  const float* Wqkv   = (const float*)d_in[5];
  const float* bqkv   = (const float*)d_in[6];
  const float* Wo     = (const float*)d_in[7];
  const float* bo     = (const float*)d_in[8];
  const float* W1     = (const float*)d_in[9];
  const float* b1     = (const float*)d_in[10];
  const float* W2     = (const float*)d_in[11];
  const float* b2     = (const float*)d_in[12];
  const float* ln1g   = (const float*)d_in[13];
  const float* ln1b   = (const float*)d_in[14];
  const float* ln2g   = (const float*)d_in[15];
  const float* ln2b   = (const float*)d_in[16];
  const float* Wq     = (const float*)d_in[17];
  const float* Wk     = (const float*)d_in[18];
  const float* Wcap   = (const float*)d_in[19];
  const float* bcap   = (const float*)d_in[20];
  const float* Wctx   = (const float*)d_in[21];
  const float* bctx   = (const float*)d_in[22];

  char* ws = (char*)d_ws;
  size_t off = 0;
  auto take = [&](size_t bytes) -> void* {
    void* p = ws + off;
    off += (bytes + 255) & ~(size_t)255;
    return p;
  };
  float* dr   = (float*)take((size_t)NT * 4);
  float* c0   = (float*)take((size_t)NT * 4);
  float* c1   = (float*)take((size_t)NT * 4);
  float* P    = (float*)take((size_t)NB * NN * NN * 4);
  unsigned* rng = (unsigned*)take((size_t)NSTEP * 2 * 4);
  float* h    = (float*)take((size_t)NT * ND * 4);
  float* qkv  = (float*)take((size_t)NT * 384 * 4);
  float* att  = (float*)take((size_t)NT * ND * 4);
  float* kmat = (float*)take((size_t)NT * ND * 4);
  float* gctx = (float*)take((size_t)NB * ND * 4);
  double* M   = (double*)take((size_t)ND * ND * 8);
  double* u   = (double*)take((size_t)ND * 8);
  double* t1  = (double*)take((size_t)ND * 8);
  double* wu  = (double*)take((size_t)ND * 8);
  double* t2  = (double*)take((size_t)NB * ND * 8);
  double* vb  = (double*)take((size_t)NB * ND * 8);
  double* W1T   = (double*)take((size_t)NL * NF * ND * 8);   // f64: phase-1 cvt-free
  float*  W2T   = (float*)take((size_t)NL * NF * ND * 4);    // f32: L2-friendly phase-2
  double* WqkvT = (double*)take((size_t)NL * 384 * ND * 8);
  double* WoT   = (double*)take((size_t)NL * ND * ND * 8);
  double* WkT   = (double*)take((size_t)ND * ND * 8);
  double* h64T  = (double*)take((size_t)NT * ND * 8);        // [blk8][k][t] post-LN1 acts
  float* KMT = qkv;   // alias: qkv (39.3 MB) dead after attention+oln; KMT = 13.1 MB
  float* gum = h;     // alias: h+qkv region (52 MB) >= gum (41 MB); written after k_P

  k_rng<<<1, 64, 0, stream>>>(rng);
  k_trall<<<(TRTOT + 255) / 256, 256, 0, stream>>>(W1, W2, Wqkv, Wo, Wk, W1T, W2T, WqkvT, WoT, WkT);
  k_embed<<<(NT * ND) / 256, 256, 0, stream>>>(coords, dem, cap, eW, eb, h, dr);
  for (int i = 0; i < NL; ++i) {
    k_qkv<<<NT / QT, 384, 0, stream>>>(h, WqkvT + (size_t)i * 384 * ND, bqkv + (size_t)i * 384, qkv);
    k_attn<<<NB * NH, 256, 0, stream>>>(qkv, att);
    k_oln<<<NT / OT, 128, 0, stream>>>(att, WoT + (size_t)i * ND * ND, bo + (size_t)i * ND,
                                       ln1g + (size_t)i * ND, ln1b + (size_t)i * ND, h, h64T);
    k_ffn<<<NT / FT, 512, 0, stream>>>(h, h64T, W1T + (size_t)i * NF * ND, b1 + (size_t)i * NF,
                                       W2T + (size_t)i * ND * NF, b2 + (size_t)i * ND,
                                       ln2g + (size_t)i * ND, ln2b + (size_t)i * ND);
  }
  k_gctx<<<NB, 128, 0, stream>>>(h, gctx);
  k_kmat<<<NT / KT, 128, 0, stream>>>(h, WkT, kmat);
  k_prep1<<<1, 128, 0, stream>>>(Wctx, bcap, Wcap, bctx, t1, wu);
  k_M<<<ND, 128, 0, stream>>>(Wq, Wctx, M);
  k_u<<<1, 128, 0, stream>>>(Wq, wu, u);
  k_t2<<<NB, 128, 0, stream>>>(Wctx, gctx, t2);
  k_vb<<<NB, 128, 0, stream>>>(Wq, t2, t1, vb);
  k_c01<<<NT / 256, 256, 0, stream>>>(kmat, vb, u, c0, c1);
  k_KM<<<NT / KT, 128, 0, stream>>>(kmat, M, KMT);
  k_P<<<NB * 25, 256, 0, stream>>>(KMT, h, P);
  k_gum<<<(NSTEP * NT + 255) / 256, 256, 0, stream>>>(rng, gum);
  k_decode<<<NB, 64, 0, stream>>>(P, c0, c1, dr, gum, (float*)d_out);
}